// Round 12
// baseline (193.619 us; speedup 1.0000x reference)
//
#include <hip/hip_runtime.h>
#include <hip/hip_bf16.h>

typedef unsigned short u16;
typedef __attribute__((ext_vector_type(8))) short short8;
typedef __attribute__((ext_vector_type(2))) float f32x2;
typedef __attribute__((ext_vector_type(4))) float f32x4;
typedef __attribute__((ext_vector_type(16))) float f32x16;

#define NH 16
#define HD 64
#define SEQ 2048
#define NBATCH 2
#define DM 1024

#define GLOAD_LDS(g, l)                                                              \
  __builtin_amdgcn_global_load_lds((__attribute__((address_space(1))) const void*)(g), \
                                   (__attribute__((address_space(3))) void*)(l), 16, 0, 0)

__device__ __forceinline__ u16 f2bf(float f) {
  __hip_bfloat16 h = __float2bfloat16(f);
  return *reinterpret_cast<u16*>(&h);
}
__device__ __forceinline__ float bf2f(u16 u) {
  union { unsigned int i; float f; } v; v.i = ((unsigned int)u) << 16; return v.f;
}
__device__ __forceinline__ f32x4 mfma16(short8 a, short8 b, f32x4 c) {
  return __builtin_amdgcn_mfma_f32_16x16x32_bf16(a, b, c, 0, 0, 0);
}
__device__ __forceinline__ f32x16 mfma32(short8 a, short8 b, f32x16 c) {
  return __builtin_amdgcn_mfma_f32_32x32x16_bf16(a, b, c, 0, 0, 0);
}

// ---------------- f32 -> bf16 convert (vectorized) ----------------
__global__ void k_convert(const float* __restrict__ src, u16* __restrict__ dst, int n4) {
  int i = blockIdx.x * blockDim.x + threadIdx.x;
  if (i >= n4) return;
  float4 v = reinterpret_cast<const float4*>(src)[i];
  union { u16 h[4]; unsigned long long u; } o;
  o.h[0] = f2bf(v.x); o.h[1] = f2bf(v.y); o.h[2] = f2bf(v.z); o.h[3] = f2bf(v.w);
  reinterpret_cast<unsigned long long*>(dst)[i] = o.u;
}

// ---------------- f32 [R][C] -> bf16 [C][R] transpose ----------------
__global__ void k_transpose(const float* __restrict__ src, u16* __restrict__ dst, int R, int C) {
  __shared__ float t[32][33];
  int c0 = blockIdx.x * 32, r0 = blockIdx.y * 32;
  int tx = threadIdx.x, ty = threadIdx.y;
#pragma unroll
  for (int i = 0; i < 4; ++i)
    t[ty + 8 * i][tx] = src[(size_t)(r0 + ty + 8 * i) * C + c0 + tx];
  __syncthreads();
#pragma unroll
  for (int i = 0; i < 4; ++i)
    dst[(size_t)(c0 + ty + 8 * i) * R + r0 + tx] = f2bf(t[tx][ty + 8 * i]);
}

// ---------------- RoPE sin/cos table: [pos][i] -> (sin, cos) ----------------
__global__ void k_sincos(float2* __restrict__ sc) {
  int idx = blockIdx.x * 256 + threadIdx.x;  // 2048*32
  int p = idx >> 5, i = idx & 31;
  const float l2ts = 0.41524101186092029f;  // log2(10000)/32
  float inv = exp2f(-(float)i * l2ts);      // 10000^(-i/32)
  float arg = (float)p * inv;
  float s, c;
  sincosf(arg, &s, &c);
  sc[idx] = make_float2(s, c);
}

// ---------------- RoPE in-place on Q (scaled 1/8) and K ----------------
// Separate streaming kernel (coalesced uint4 loads): ~7us. Fusing this into
// the GEMM epilogue costs ~45us of uncoalesced segpos/sc gathers — R6 post-mortem.
__global__ void k_rope(u16* __restrict__ Q, u16* __restrict__ K,
                       const int* __restrict__ segpos, const float2* __restrict__ sc) {
  int rid = blockIdx.x * 256 + threadIdx.x;  // 2 * B*H*S rows
  u16* buf = (rid < NBATCH * NH * SEQ) ? Q : K;
  float qs = (rid < NBATCH * NH * SEQ) ? 0.125f : 1.0f;
  int r = rid & (NBATCH * NH * SEQ - 1);
  int b = r >> 15;  // / (NH*SEQ)
  int s = r & (SEQ - 1);
  int pos = segpos[b * SEQ + s];
  const float2* scp = sc + (size_t)pos * 32;
  u16* row = buf + (size_t)r * HD;
  uint4 v[8];
#pragma unroll
  for (int i = 0; i < 8; ++i) v[i] = reinterpret_cast<uint4*>(row)[i];
  u16* e = reinterpret_cast<u16*>(v);
#pragma unroll
  for (int i = 0; i < 32; ++i) {
    float a = bf2f(e[i]), bq = bf2f(e[i + 32]);
    float2 t = scp[i];
    float na = (a * t.y - bq * t.x) * qs;
    float nb = (bq * t.y + a * t.x) * qs;
    e[i] = f2bf(na); e[i + 32] = f2bf(nb);
  }
#pragma unroll
  for (int i = 0; i < 8; ++i) reinterpret_cast<uint4*>(row)[i] = v[i];
}

// ---------------- bf16 MFMA GEMM, 128x128 tile, BK=64, global_load_lds ----------------
// A [M][1024] row-major bf16; Bt [N][1024] row-major bf16 (= B^T).
// MODE 0: epilogue scatters in_proj into Q/K [b][h][s][64] and Vt [b][h][64][s].
// MODE 1: plain f32 store to out [M][N].
// XCD-aware block swizzle (T1): grid sizes 768/256 are %8==0 -> bijective.
template <int MODE>
__global__ __launch_bounds__(256) void k_gemm(const u16* __restrict__ A, const u16* __restrict__ Bt,
                                              int N, u16* __restrict__ q, u16* __restrict__ kk,
                                              u16* __restrict__ vt, float* __restrict__ out) {
  __shared__ alignas(16) u16 As[128][64];
  __shared__ alignas(16) u16 Bs[128][64];
  const int K = 1024;
  int tid = threadIdx.x;
  int lane = tid & 63, w = tid >> 6;
  int wr = w >> 1, wc = w & 1;
  int col = lane & 15, grp = lane >> 4;
  int bid = blockIdx.y * gridDim.x + blockIdx.x;
  int qq = (gridDim.x * gridDim.y) >> 3;
  int swz = (bid & 7) * qq + (bid >> 3);
  int m0 = (swz / gridDim.x) * 128;
  int n0 = (swz % gridDim.x) * 128;
  // global_load_lds chunk geometry: chunk = 1KB = 8 rows of 64 bf16;
  // lane writes LDS bytes [chunk*1024 + lane*16) -> row chunk*8+(lane>>3), col (lane&7)*8.
  int crow = lane >> 3, ccol = (lane & 7) * 8;
  f32x4 zero4 = {0.f, 0.f, 0.f, 0.f};
  f32x4 acc[4][4];
#pragma unroll
  for (int i = 0; i < 4; ++i)
#pragma unroll
    for (int j = 0; j < 4; ++j) acc[i][j] = zero4;

  for (int k0 = 0; k0 < K; k0 += 64) {
    __syncthreads();  // previous compute done before overwrite
#pragma unroll
    for (int c = 0; c < 4; ++c) {
      int chunk = w * 4 + c;
      int r = chunk * 8 + crow;
      GLOAD_LDS(&A[(size_t)(m0 + r) * K + k0 + ccol], &As[0][0] + chunk * 512);
      GLOAD_LDS(&Bt[(size_t)(n0 + r) * K + k0 + ccol], &Bs[0][0] + chunk * 512);
    }
    __syncthreads();  // vmcnt drained by barrier -> tiles visible
#pragma unroll
    for (int kf = 0; kf < 2; ++kf) {
      short8 af[4], bfr[4];
#pragma unroll
      for (int i = 0; i < 4; ++i)
        af[i] = *reinterpret_cast<const short8*>(&As[wr * 64 + i * 16 + col][kf * 32 + grp * 8]);
#pragma unroll
      for (int i = 0; i < 4; ++i)
        bfr[i] = *reinterpret_cast<const short8*>(&Bs[wc * 64 + i * 16 + col][kf * 32 + grp * 8]);
#pragma unroll
      for (int mi = 0; mi < 4; ++mi)
#pragma unroll
        for (int ni = 0; ni < 4; ++ni) acc[mi][ni] = mfma16(af[mi], bfr[ni], acc[mi][ni]);
    }
  }
#pragma unroll
  for (int mi = 0; mi < 4; ++mi)
#pragma unroll
    for (int ni = 0; ni < 4; ++ni)
#pragma unroll
      for (int j = 0; j < 4; ++j) {
        int m = m0 + wr * 64 + mi * 16 + grp * 4 + j;
        int n = n0 + wc * 64 + ni * 16 + col;
        float v = acc[mi][ni][j];
        if (MODE == 0) {
          int b = m >> 11, s = m & 2047;
          int h = n / 192, f = n - h * 192;
          u16 bv = f2bf(v);
          if (f < 64)
            q[(((size_t)(b * NH + h) * SEQ + s) << 6) + f] = bv;
          else if (f < 128)
            kk[(((size_t)(b * NH + h) * SEQ + s) << 6) + (f - 64)] = bv;
          else
            vt[(((size_t)(b * NH + h) * HD + (f - 128)) << 11) + s] = bv;
        } else {
          out[(size_t)m * N + n] = v;
        }
      }
}

// ---------------- flash attention, causal, softcap 50 ----------------
// R9 structure (known-good 73.6us): 4-wave blocks, grid 1024, uniform-work
// pairing (63-i, i), split-KV x4, serial combine. Packed-f32 softmax (R11:
// real inst cut, VALUBusy -16%). R12 single change: K-ONLY register
// prefetch — kn loads issue FIRST in the body (clamped address, no branch),
// consumed next iteration; #pragma unroll 2 renames the kc=kn rotation away.
// K-load latency then hides under QK+SM+PV instead of stalling each tile.
// R8 lesson: K+V double-buffer (+32 regs, for(;;)+break CFG) spilled; this
// is +16 regs with straight-line CFG. Spill tripwire: WRITE_SIZE 8.2MB.
// R10 lesson: 4 waves/SIMD is the occupancy ceiling for this state size.
__global__ __launch_bounds__(256, 4) void k_attn(const u16* __restrict__ Q,
                                                 const u16* __restrict__ K,
                                                 const u16* __restrict__ Vt,
                                                 u16* __restrict__ X) {
  int lin = blockIdx.x;          // 0..1023
  int xcd = lin & 7;             // dispatch round-robins XCDs
  int jj = lin >> 3;             // 0..127
  int bh = xcd * 4 + (jj & 3);   // 4 heads per XCD -> K+V 2MB/XCD, L2-resident
  int iq = jj >> 2;              // 0..31
  int tid = threadIdx.x, lane = tid & 63, w = tid >> 6;
  int ql = lane & 31, hi = lane >> 5;
  const u16* Qb = Q + (size_t)bh * SEQ * HD;
  const u16* Kb = K + (size_t)bh * SEQ * HD;
  const u16* Vb = Vt + (size_t)bh * HD * SEQ;
  int b = bh >> 4, h = bh & 15;
  size_t ob = (size_t)b * SEQ * DM + (size_t)h * HD;

  __shared__ float cbuf[64][34];  // combine: 16+16+1 f32 per lane

  const float L2E = 1.4426950408889634f;
  const f32x2 C32 = {-1.9235933878519513e-4f, -1.9235933878519513e-4f};  // -L2E/7500
  const f32x2 C52 = {3.0777494205630686e-8f, 3.0777494205630686e-8f};    // 2*L2E/(15*50^4)
  const f32x2 L2E2 = {L2E, L2E};

  for (int half = 0; half < 2; ++half) {
    int qc = half ? iq : 63 - iq;  // pair sums to 65 tiles -> uniform blocks
    int qbase = qc * 32;

    // Q fragments (B-operand): Q[qbase+ql][d0*16 + hi*8 .. +8]
    short8 qf[4];
#pragma unroll
    for (int d0 = 0; d0 < 4; ++d0)
      qf[d0] = *reinterpret_cast<const short8*>(&Qb[(size_t)(qbase + ql) * HD + d0 * 16 + hi * 8]);

    f32x16 xacc0, xacc1;
#pragma unroll
    for (int r = 0; r < 16; ++r) { xacc0[r] = 0.f; xacc1[r] = 0.f; }
    f32x2 lsum2 = {0.f, 0.f};

    int nkt = qc + 1;  // KV tiles of 32
    // prime K for the wave's first tile (clamped: some waves have no tiles)
    short8 kc[4];
    {
      int kt0 = (w < nkt) ? w : (nkt - 1);
#pragma unroll
      for (int d0 = 0; d0 < 4; ++d0)
        kc[d0] = *reinterpret_cast<const short8*>(
            &Kb[(size_t)(kt0 * 32 + ql) * HD + d0 * 16 + hi * 8]);
    }

#pragma unroll 2
    for (int kt = w; kt < nkt; kt += 4) {
      int kbase = kt * 32;
      bool diag = (kt == qc);  // wave-uniform

      // prefetch next K tile (clamped address, unconditional -> clean CFG)
      short8 kn[4];
      {
        int ktn = kt + 4;
        if (ktn > nkt - 1) ktn = nkt - 1;
#pragma unroll
        for (int d0 = 0; d0 < 4; ++d0)
          kn[d0] = *reinterpret_cast<const short8*>(
              &Kb[(size_t)(ktn * 32 + ql) * HD + d0 * 16 + hi * 8]);
      }

      // S^T[k-rel][q] += K . Q^T over 4 d-chunks (consumes kc, loaded last iter)
      f32x16 sacc;
#pragma unroll
      for (int r = 0; r < 16; ++r) sacc[r] = 0.f;
#pragma unroll
      for (int d0 = 0; d0 < 4; ++d0) sacc = mfma32(kc[d0], qf[d0], sacc);

      // V fragments (latency hides under softmax): V^T[dh*32+ql][k-slice]
      short8 vf[2][2];
#pragma unroll
      for (int c = 0; c < 2; ++c)
#pragma unroll
        for (int dh = 0; dh < 2; ++dh)
          vf[c][dh] = *reinterpret_cast<const short8*>(
              &Vb[(size_t)(dh * 32 + ql) * SEQ + kbase + c * 16 + hi * 8]);

      // softcap + exp (fixed max 0), PACKED over r-pairs:
      // p = exp2(s*(L2E + t*(C3 + t*C5))), t = s*s  -> v_pk_mul/fma_f32
      float p[16];
#pragma unroll
      for (int r2 = 0; r2 < 8; ++r2) {
        f32x2 s2 = {sacc[2 * r2], sacc[2 * r2 + 1]};
        f32x2 t2 = s2 * s2;
        f32x2 u2 = __builtin_elementwise_fma(t2, C52, C32);
        u2 = __builtin_elementwise_fma(t2, u2, L2E2);
        f32x2 v2 = s2 * u2;
        float p0 = exp2f(v2.x), p1 = exp2f(v2.y);
        if (diag) {
          int r = 2 * r2;
          int kpos0 = kbase + (r & 3) + 8 * (r >> 2) + 4 * hi;
          int kpos1 = kbase + ((r + 1) & 3) + 8 * ((r + 1) >> 2) + 4 * hi;
          if (kpos0 > qbase + ql) p0 = 0.f;
          if (kpos1 > qbase + ql) p1 = 0.f;
        }
        p[2 * r2] = p0;
        p[2 * r2 + 1] = p1;
        lsum2 += (f32x2){p0, p1};
      }

      // pack P rows into PV A-fragments: chunk c = k-rel [16c, 16c+16)
      short8 pfrag[2];
#pragma unroll
      for (int c = 0; c < 2; ++c) {
        unsigned int a0, a1, b0, b1;
        asm("v_cvt_pk_bf16_f32 %0, %1, %2" : "=v"(a0) : "v"(p[8 * c + 0]), "v"(p[8 * c + 1]));
        asm("v_cvt_pk_bf16_f32 %0, %1, %2" : "=v"(a1) : "v"(p[8 * c + 2]), "v"(p[8 * c + 3]));
        asm("v_cvt_pk_bf16_f32 %0, %1, %2" : "=v"(b0) : "v"(p[8 * c + 4]), "v"(p[8 * c + 5]));
        asm("v_cvt_pk_bf16_f32 %0, %1, %2" : "=v"(b1) : "v"(p[8 * c + 6]), "v"(p[8 * c + 7]));
        // dst' = {dst.lo, src.lo}; src' = {dst.hi, src.hi}
        asm("v_permlane32_swap_b32 %0, %1" : "+v"(a0), "+v"(b0));
        asm("v_permlane32_swap_b32 %0, %1" : "+v"(a1), "+v"(b1));
        union { unsigned int u[4]; short8 s8; } pk;
        pk.u[0] = a0; pk.u[1] = a1; pk.u[2] = b0; pk.u[3] = b1;
        pfrag[c] = pk.s8;
      }

      // PV: X[q][d] += P . V  (two d-halves)
#pragma unroll
      for (int c = 0; c < 2; ++c) {
        xacc0 = mfma32(pfrag[c], vf[c][0], xacc0);
        xacc1 = mfma32(pfrag[c], vf[c][1], xacc1);
      }

      // rotate prefetch buffer (renamed away by unroll-2)
#pragma unroll
      for (int d0 = 0; d0 < 4; ++d0) kc[d0] = kn[d0];
    }
    float lsum = lsum2.x + lsum2.y;

    // ---- combine the 4 waves' partials (plain sums; M=0 softmax) ----
    __syncthreads();
    for (int src = 1; src < 4; ++src) {
      if (w == src) {
#pragma unroll
        for (int r = 0; r < 16; ++r) {
          if (src == 1) { cbuf[lane][r] = xacc0[r]; cbuf[lane][16 + r] = xacc1[r]; }
          else { cbuf[lane][r] += xacc0[r]; cbuf[lane][16 + r] += xacc1[r]; }
        }
        if (src == 1) cbuf[lane][32] = lsum; else cbuf[lane][32] += lsum;
      }
      __syncthreads();
    }

    if (w == 0) {
#pragma unroll
      for (int r = 0; r < 16; ++r) { xacc0[r] += cbuf[lane][r]; xacc1[r] += cbuf[lane][16 + r]; }
      lsum += cbuf[lane][32];
      // lanes q and q+32 hold the two k-half partials of row q
      lsum += __shfl_xor(lsum, 32, 64);
      float rinv = __builtin_amdgcn_rcpf(lsum);  // valid for q = ql on every lane

#pragma unroll
      for (int r = 0; r < 16; ++r) {
        int qrel = (r & 3) + 8 * (r >> 2) + 4 * hi;
        float rv = __shfl(rinv, qrel, 64);
        size_t row = ob + (size_t)(qbase + qrel) * DM;
        X[row + ql] = f2bf(xacc0[r] * rv);
        X[row + 32 + ql] = f2bf(xacc1[r] * rv);
      }
    }
    __syncthreads();  // cbuf safe for reuse by next half
  }
}

extern "C" void kernel_launch(void* const* d_in, const int* in_sizes, int n_in,
                              void* d_out, int out_size, void* d_ws, size_t ws_size,
                              hipStream_t stream) {
  const float* inputs = (const float*)d_in[0];
  const int* segpos = (const int*)d_in[1];
  // d_in[2] = mask: causal tril, known analytically — unused.
  const float* w_in = (const float*)d_in[3];
  const float* w_out = (const float*)d_in[4];
  float* out = (float*)d_out;
  char* ws = (char*)d_ws;

  size_t o = 0;
  u16* Xbf = (u16*)(ws + o); o += (size_t)4096 * 1024 * 2;   // inputs bf16; reused as attn output
  u16* WinT = (u16*)(ws + o); o += (size_t)3072 * 1024 * 2;  // w_in^T bf16
  u16* WoutT = (u16*)(ws + o); o += (size_t)1024 * 1024 * 2; // w_out^T bf16
  u16* Qb = (u16*)(ws + o); o += (size_t)NBATCH * NH * SEQ * HD * 2;
  u16* Kb = (u16*)(ws + o); o += (size_t)NBATCH * NH * SEQ * HD * 2;
  u16* Vt = (u16*)(ws + o); o += (size_t)NBATCH * NH * HD * SEQ * 2;
  float2* SC = (float2*)(ws + o); o += (size_t)SEQ * 32 * sizeof(float2);

  k_convert<<<4096, 256, 0, stream>>>(inputs, Xbf, 1048576);
  k_transpose<<<dim3(96, 32), dim3(32, 8), 0, stream>>>(w_in, WinT, 1024, 3072);
  k_transpose<<<dim3(32, 32), dim3(32, 8), 0, stream>>>(w_out, WoutT, 1024, 1024);
  k_sincos<<<256, 256, 0, stream>>>(SC);
  k_gemm<0><<<dim3(24, 32), 256, 0, stream>>>(Xbf, WinT, 3072, Qb, Kb, Vt, nullptr);
  k_rope<<<512, 256, 0, stream>>>(Qb, Kb, segpos, SC);
  k_attn<<<1024, 256, 0, stream>>>(Qb, Kb, Vt, Xbf);
  k_gemm<1><<<dim3(8, 32), 256, 0, stream>>>(Xbf, WoutT, 1024, nullptr, nullptr, nullptr, out);
}

// Round 13
// 175.980 us; speedup vs baseline: 1.1002x; 1.1002x over previous
//
#include <hip/hip_runtime.h>
#include <hip/hip_bf16.h>

typedef unsigned short u16;
typedef __attribute__((ext_vector_type(8))) short short8;
typedef __attribute__((ext_vector_type(2))) float f32x2;
typedef __attribute__((ext_vector_type(4))) float f32x4;
typedef __attribute__((ext_vector_type(16))) float f32x16;

#define NH 16
#define HD 64
#define SEQ 2048
#define NBATCH 2
#define DM 1024

#define GLOAD_LDS(g, l)                                                              \
  __builtin_amdgcn_global_load_lds((__attribute__((address_space(1))) const void*)(g), \
                                   (__attribute__((address_space(3))) void*)(l), 16, 0, 0)

__device__ __forceinline__ u16 f2bf(float f) {
  __hip_bfloat16 h = __float2bfloat16(f);
  return *reinterpret_cast<u16*>(&h);
}
__device__ __forceinline__ float bf2f(u16 u) {
  union { unsigned int i; float f; } v; v.i = ((unsigned int)u) << 16; return v.f;
}
__device__ __forceinline__ f32x4 mfma16(short8 a, short8 b, f32x4 c) {
  return __builtin_amdgcn_mfma_f32_16x16x32_bf16(a, b, c, 0, 0, 0);
}
__device__ __forceinline__ f32x16 mfma32(short8 a, short8 b, f32x16 c) {
  return __builtin_amdgcn_mfma_f32_32x32x16_bf16(a, b, c, 0, 0, 0);
}

// ---------------- f32 -> bf16 convert (vectorized) ----------------
__global__ void k_convert(const float* __restrict__ src, u16* __restrict__ dst, int n4) {
  int i = blockIdx.x * blockDim.x + threadIdx.x;
  if (i >= n4) return;
  float4 v = reinterpret_cast<const float4*>(src)[i];
  union { u16 h[4]; unsigned long long u; } o;
  o.h[0] = f2bf(v.x); o.h[1] = f2bf(v.y); o.h[2] = f2bf(v.z); o.h[3] = f2bf(v.w);
  reinterpret_cast<unsigned long long*>(dst)[i] = o.u;
}

// ---------------- f32 [R][C] -> bf16 [C][R] transpose ----------------
__global__ void k_transpose(const float* __restrict__ src, u16* __restrict__ dst, int R, int C) {
  __shared__ float t[32][33];
  int c0 = blockIdx.x * 32, r0 = blockIdx.y * 32;
  int tx = threadIdx.x, ty = threadIdx.y;
#pragma unroll
  for (int i = 0; i < 4; ++i)
    t[ty + 8 * i][tx] = src[(size_t)(r0 + ty + 8 * i) * C + c0 + tx];
  __syncthreads();
#pragma unroll
  for (int i = 0; i < 4; ++i)
    dst[(size_t)(c0 + ty + 8 * i) * R + r0 + tx] = f2bf(t[tx][ty + 8 * i]);
}

// ---------------- RoPE sin/cos table: [pos][i] -> (sin, cos) ----------------
__global__ void k_sincos(float2* __restrict__ sc) {
  int idx = blockIdx.x * 256 + threadIdx.x;  // 2048*32
  int p = idx >> 5, i = idx & 31;
  const float l2ts = 0.41524101186092029f;  // log2(10000)/32
  float inv = exp2f(-(float)i * l2ts);      // 10000^(-i/32)
  float arg = (float)p * inv;
  float s, c;
  sincosf(arg, &s, &c);
  sc[idx] = make_float2(s, c);
}

// ---------------- RoPE in-place on Q (scaled 1/8) and K ----------------
// Separate streaming kernel (coalesced uint4 loads): ~7us. Fusing this into
// the GEMM epilogue costs ~45us of uncoalesced segpos/sc gathers — R6 post-mortem.
__global__ void k_rope(u16* __restrict__ Q, u16* __restrict__ K,
                       const int* __restrict__ segpos, const float2* __restrict__ sc) {
  int rid = blockIdx.x * 256 + threadIdx.x;  // 2 * B*H*S rows
  u16* buf = (rid < NBATCH * NH * SEQ) ? Q : K;
  float qs = (rid < NBATCH * NH * SEQ) ? 0.125f : 1.0f;
  int r = rid & (NBATCH * NH * SEQ - 1);
  int b = r >> 15;  // / (NH*SEQ)
  int s = r & (SEQ - 1);
  int pos = segpos[b * SEQ + s];
  const float2* scp = sc + (size_t)pos * 32;
  u16* row = buf + (size_t)r * HD;
  uint4 v[8];
#pragma unroll
  for (int i = 0; i < 8; ++i) v[i] = reinterpret_cast<uint4*>(row)[i];
  u16* e = reinterpret_cast<u16*>(v);
#pragma unroll
  for (int i = 0; i < 32; ++i) {
    float a = bf2f(e[i]), bq = bf2f(e[i + 32]);
    float2 t = scp[i];
    float na = (a * t.y - bq * t.x) * qs;
    float nb = (bq * t.y + a * t.x) * qs;
    e[i] = f2bf(na); e[i + 32] = f2bf(nb);
  }
#pragma unroll
  for (int i = 0; i < 8; ++i) reinterpret_cast<uint4*>(row)[i] = v[i];
}

// ---------------- bf16 MFMA GEMM, 128x128 tile, BK=64, global_load_lds ----------------
// A [M][1024] row-major bf16; Bt [N][1024] row-major bf16 (= B^T).
// MODE 0: epilogue scatters in_proj into Q/K [b][h][s][64] and TILED
//         Vt [b][h][kt=s/32][d=64][kv=s%32]  (4KB contiguous per KV tile —
//         R13: the old [d][s] layout made attn V-loads 64-distinct-cacheline
//         gathers; TA line-throughput was the attn serializer).
// MODE 1: plain f32 store to out [M][N].
// XCD-aware block swizzle (T1): grid sizes 768/256 are %8==0 -> bijective.
template <int MODE>
__global__ __launch_bounds__(256) void k_gemm(const u16* __restrict__ A, const u16* __restrict__ Bt,
                                              int N, u16* __restrict__ q, u16* __restrict__ kk,
                                              u16* __restrict__ vt, float* __restrict__ out) {
  __shared__ alignas(16) u16 As[128][64];
  __shared__ alignas(16) u16 Bs[128][64];
  const int K = 1024;
  int tid = threadIdx.x;
  int lane = tid & 63, w = tid >> 6;
  int wr = w >> 1, wc = w & 1;
  int col = lane & 15, grp = lane >> 4;
  int bid = blockIdx.y * gridDim.x + blockIdx.x;
  int qq = (gridDim.x * gridDim.y) >> 3;
  int swz = (bid & 7) * qq + (bid >> 3);
  int m0 = (swz / gridDim.x) * 128;
  int n0 = (swz % gridDim.x) * 128;
  // global_load_lds chunk geometry: chunk = 1KB = 8 rows of 64 bf16;
  // lane writes LDS bytes [chunk*1024 + lane*16) -> row chunk*8+(lane>>3), col (lane&7)*8.
  int crow = lane >> 3, ccol = (lane & 7) * 8;
  f32x4 zero4 = {0.f, 0.f, 0.f, 0.f};
  f32x4 acc[4][4];
#pragma unroll
  for (int i = 0; i < 4; ++i)
#pragma unroll
    for (int j = 0; j < 4; ++j) acc[i][j] = zero4;

  for (int k0 = 0; k0 < K; k0 += 64) {
    __syncthreads();  // previous compute done before overwrite
#pragma unroll
    for (int c = 0; c < 4; ++c) {
      int chunk = w * 4 + c;
      int r = chunk * 8 + crow;
      GLOAD_LDS(&A[(size_t)(m0 + r) * K + k0 + ccol], &As[0][0] + chunk * 512);
      GLOAD_LDS(&Bt[(size_t)(n0 + r) * K + k0 + ccol], &Bs[0][0] + chunk * 512);
    }
    __syncthreads();  // vmcnt drained by barrier -> tiles visible
#pragma unroll
    for (int kf = 0; kf < 2; ++kf) {
      short8 af[4], bfr[4];
#pragma unroll
      for (int i = 0; i < 4; ++i)
        af[i] = *reinterpret_cast<const short8*>(&As[wr * 64 + i * 16 + col][kf * 32 + grp * 8]);
#pragma unroll
      for (int i = 0; i < 4; ++i)
        bfr[i] = *reinterpret_cast<const short8*>(&Bs[wc * 64 + i * 16 + col][kf * 32 + grp * 8]);
#pragma unroll
      for (int mi = 0; mi < 4; ++mi)
#pragma unroll
        for (int ni = 0; ni < 4; ++ni) acc[mi][ni] = mfma16(af[mi], bfr[ni], acc[mi][ni]);
    }
  }
#pragma unroll
  for (int mi = 0; mi < 4; ++mi)
#pragma unroll
    for (int ni = 0; ni < 4; ++ni)
#pragma unroll
      for (int j = 0; j < 4; ++j) {
        int m = m0 + wr * 64 + mi * 16 + grp * 4 + j;
        int n = n0 + wc * 64 + ni * 16 + col;
        float v = acc[mi][ni][j];
        if (MODE == 0) {
          int b = m >> 11, s = m & 2047;
          int h = n / 192, f = n - h * 192;
          u16 bv = f2bf(v);
          if (f < 64)
            q[(((size_t)(b * NH + h) * SEQ + s) << 6) + f] = bv;
          else if (f < 128)
            kk[(((size_t)(b * NH + h) * SEQ + s) << 6) + (f - 64)] = bv;
          else
            vt[(size_t)(b * NH + h) * (HD * SEQ) + (size_t)(s >> 5) * 2048 +
               (f - 128) * 32 + (s & 31)] = bv;
        } else {
          out[(size_t)m * N + n] = v;
        }
      }
}

// ---------------- flash attention, causal, softcap 50 ----------------
// R9 structure (known-good 73.6us): 4-wave blocks, grid 1024, uniform-work
// pairing (63-i, i), split-KV x4, serial combine. Packed-f32 softmax (R11).
// R13 single change: TILED Vt layout [b][h][kt][64][32] — each KV tile is a
// contiguous 4KB block, so V fragment loads touch 32 shared cachelines
// instead of 64 distinct 4KB-strided lines per instruction. R12 accounting
// showed TA line-throughput (~133K line-cycles/CU) matched elapsed time.
// No prefetch (R8/R12 spilled). 4 waves/SIMD is the occupancy ceiling (R10).
__global__ __launch_bounds__(256, 4) void k_attn(const u16* __restrict__ Q,
                                                 const u16* __restrict__ K,
                                                 const u16* __restrict__ Vt,
                                                 u16* __restrict__ X) {
  int lin = blockIdx.x;          // 0..1023
  int xcd = lin & 7;             // dispatch round-robins XCDs
  int jj = lin >> 3;             // 0..127
  int bh = xcd * 4 + (jj & 3);   // 4 heads per XCD -> K+V 2MB/XCD, L2-resident
  int iq = jj >> 2;              // 0..31
  int tid = threadIdx.x, lane = tid & 63, w = tid >> 6;
  int ql = lane & 31, hi = lane >> 5;
  const u16* Qb = Q + (size_t)bh * SEQ * HD;
  const u16* Kb = K + (size_t)bh * SEQ * HD;
  const u16* Vb = Vt + (size_t)bh * HD * SEQ;
  int b = bh >> 4, h = bh & 15;
  size_t ob = (size_t)b * SEQ * DM + (size_t)h * HD;

  __shared__ float cbuf[64][34];  // combine: 16+16+1 f32 per lane

  const float L2E = 1.4426950408889634f;
  const f32x2 C32 = {-1.9235933878519513e-4f, -1.9235933878519513e-4f};  // -L2E/7500
  const f32x2 C52 = {3.0777494205630686e-8f, 3.0777494205630686e-8f};    // 2*L2E/(15*50^4)
  const f32x2 L2E2 = {L2E, L2E};

  for (int half = 0; half < 2; ++half) {
    int qc = half ? iq : 63 - iq;  // pair sums to 65 tiles -> uniform blocks
    int qbase = qc * 32;

    // Q fragments (B-operand): Q[qbase+ql][d0*16 + hi*8 .. +8]
    short8 qf[4];
#pragma unroll
    for (int d0 = 0; d0 < 4; ++d0)
      qf[d0] = *reinterpret_cast<const short8*>(&Qb[(size_t)(qbase + ql) * HD + d0 * 16 + hi * 8]);

    f32x16 xacc0, xacc1;
#pragma unroll
    for (int r = 0; r < 16; ++r) { xacc0[r] = 0.f; xacc1[r] = 0.f; }
    f32x2 lsum2 = {0.f, 0.f};

    int nkt = qc + 1;  // KV tiles of 32
    for (int kt = w; kt < nkt; kt += 4) {
      int kbase = kt * 32;
      bool diag = (kt == qc);  // wave-uniform

      // K fragments (A-operand): K[kbase+ql][d0*16 + hi*8 .. +8]
      // (K tile = 32 contiguous rows = 4KB: 32 shared lines, L0-cached)
      short8 kf[4];
#pragma unroll
      for (int d0 = 0; d0 < 4; ++d0)
        kf[d0] = *reinterpret_cast<const short8*>(
            &Kb[(size_t)(kbase + ql) * HD + d0 * 16 + hi * 8]);

      // S^T[k-rel][q] += K . Q^T over 4 d-chunks
      f32x16 sacc;
#pragma unroll
      for (int r = 0; r < 16; ++r) sacc[r] = 0.f;
#pragma unroll
      for (int d0 = 0; d0 < 4; ++d0) sacc = mfma32(kf[d0], qf[d0], sacc);

      // V fragments from TILED layout: tile base + (dh*32+ql)*32 + c*16 + hi*8
      // (contiguous 4KB tile: per-lane stride 64B, 32 shared lines)
      const u16* Vtile = Vb + (size_t)kt * 2048;
      short8 vf[2][2];
#pragma unroll
      for (int c = 0; c < 2; ++c)
#pragma unroll
        for (int dh = 0; dh < 2; ++dh)
          vf[c][dh] = *reinterpret_cast<const short8*>(
              &Vtile[(dh * 32 + ql) * 32 + c * 16 + hi * 8]);

      // softcap + exp (fixed max 0), PACKED over r-pairs:
      // p = exp2(s*(L2E + t*(C3 + t*C5))), t = s*s  -> v_pk_mul/fma_f32
      float p[16];
#pragma unroll
      for (int r2 = 0; r2 < 8; ++r2) {
        f32x2 s2 = {sacc[2 * r2], sacc[2 * r2 + 1]};
        f32x2 t2 = s2 * s2;
        f32x2 u2 = __builtin_elementwise_fma(t2, C52, C32);
        u2 = __builtin_elementwise_fma(t2, u2, L2E2);
        f32x2 v2 = s2 * u2;
        float p0 = exp2f(v2.x), p1 = exp2f(v2.y);
        if (diag) {
          int r = 2 * r2;
          int kpos0 = kbase + (r & 3) + 8 * (r >> 2) + 4 * hi;
          int kpos1 = kbase + ((r + 1) & 3) + 8 * ((r + 1) >> 2) + 4 * hi;
          if (kpos0 > qbase + ql) p0 = 0.f;
          if (kpos1 > qbase + ql) p1 = 0.f;
        }
        p[2 * r2] = p0;
        p[2 * r2 + 1] = p1;
        lsum2 += (f32x2){p0, p1};
      }

      // pack P rows into PV A-fragments: chunk c = k-rel [16c, 16c+16)
      short8 pfrag[2];
#pragma unroll
      for (int c = 0; c < 2; ++c) {
        unsigned int a0, a1, b0, b1;
        asm("v_cvt_pk_bf16_f32 %0, %1, %2" : "=v"(a0) : "v"(p[8 * c + 0]), "v"(p[8 * c + 1]));
        asm("v_cvt_pk_bf16_f32 %0, %1, %2" : "=v"(a1) : "v"(p[8 * c + 2]), "v"(p[8 * c + 3]));
        asm("v_cvt_pk_bf16_f32 %0, %1, %2" : "=v"(b0) : "v"(p[8 * c + 4]), "v"(p[8 * c + 5]));
        asm("v_cvt_pk_bf16_f32 %0, %1, %2" : "=v"(b1) : "v"(p[8 * c + 6]), "v"(p[8 * c + 7]));
        // dst' = {dst.lo, src.lo}; src' = {dst.hi, src.hi}
        asm("v_permlane32_swap_b32 %0, %1" : "+v"(a0), "+v"(b0));
        asm("v_permlane32_swap_b32 %0, %1" : "+v"(a1), "+v"(b1));
        union { unsigned int u[4]; short8 s8; } pk;
        pk.u[0] = a0; pk.u[1] = a1; pk.u[2] = b0; pk.u[3] = b1;
        pfrag[c] = pk.s8;
      }

      // PV: X[q][d] += P . V  (two d-halves)
#pragma unroll
      for (int c = 0; c < 2; ++c) {
        xacc0 = mfma32(pfrag[c], vf[c][0], xacc0);
        xacc1 = mfma32(pfrag[c], vf[c][1], xacc1);
      }
    }
    float lsum = lsum2.x + lsum2.y;

    // ---- combine the 4 waves' partials (plain sums; M=0 softmax) ----
    __syncthreads();
    for (int src = 1; src < 4; ++src) {
      if (w == src) {
#pragma unroll
        for (int r = 0; r < 16; ++r) {
          if (src == 1) { cbuf[lane][r] = xacc0[r]; cbuf[lane][16 + r] = xacc1[r]; }
          else { cbuf[lane][r] += xacc0[r]; cbuf[lane][16 + r] += xacc1[r]; }
        }
        if (src == 1) cbuf[lane][32] = lsum; else cbuf[lane][32] += lsum;
      }
      __syncthreads();
    }

    if (w == 0) {
#pragma unroll
      for (int r = 0; r < 16; ++r) { xacc0[r] += cbuf[lane][r]; xacc1[r] += cbuf[lane][16 + r]; }
      lsum += cbuf[lane][32];
      // lanes q and q+32 hold the two k-half partials of row q
      lsum += __shfl_xor(lsum, 32, 64);
      float rinv = __builtin_amdgcn_rcpf(lsum);  // valid for q = ql on every lane

#pragma unroll
      for (int r = 0; r < 16; ++r) {
        int qrel = (r & 3) + 8 * (r >> 2) + 4 * hi;
        float rv = __shfl(rinv, qrel, 64);
        size_t row = ob + (size_t)(qbase + qrel) * DM;
        X[row + ql] = f2bf(xacc0[r] * rv);
        X[row + 32 + ql] = f2bf(xacc1[r] * rv);
      }
    }
    __syncthreads();  // cbuf safe for reuse by next half
  }
}

extern "C" void kernel_launch(void* const* d_in, const int* in_sizes, int n_in,
                              void* d_out, int out_size, void* d_ws, size_t ws_size,
                              hipStream_t stream) {
  const float* inputs = (const float*)d_in[0];
  const int* segpos = (const int*)d_in[1];
  // d_in[2] = mask: causal tril, known analytically — unused.
  const float* w_in = (const float*)d_in[3];
  const float* w_out = (const float*)d_in[4];
  float* out = (float*)d_out;
  char* ws = (char*)d_ws;

  size_t o = 0;
  u16* Xbf = (u16*)(ws + o); o += (size_t)4096 * 1024 * 2;   // inputs bf16; reused as attn output
  u16* WinT = (u16*)(ws + o); o += (size_t)3072 * 1024 * 2;  // w_in^T bf16
  u16* WoutT = (u16*)(ws + o); o += (size_t)1024 * 1024 * 2; // w_out^T bf16
  u16* Qb = (u16*)(ws + o); o += (size_t)NBATCH * NH * SEQ * HD * 2;
  u16* Kb = (u16*)(ws + o); o += (size_t)NBATCH * NH * SEQ * HD * 2;
  u16* Vt = (u16*)(ws + o); o += (size_t)NBATCH * NH * HD * SEQ * 2;
  float2* SC = (float2*)(ws + o); o += (size_t)SEQ * 32 * sizeof(float2);

  k_convert<<<4096, 256, 0, stream>>>(inputs, Xbf, 1048576);
  k_transpose<<<dim3(96, 32), dim3(32, 8), 0, stream>>>(w_in, WinT, 1024, 3072);
  k_transpose<<<dim3(32, 32), dim3(32, 8), 0, stream>>>(w_out, WoutT, 1024, 1024);
  k_sincos<<<256, 256, 0, stream>>>(SC);
  k_gemm<0><<<dim3(24, 32), 256, 0, stream>>>(Xbf, WinT, 3072, Qb, Kb, Vt, nullptr);
  k_rope<<<512, 256, 0, stream>>>(Qb, Kb, segpos, SC);
  k_attn<<<1024, 256, 0, stream>>>(Qb, Kb, Vt, Xbf);
  k_gemm<1><<<dim3(8, 32), 256, 0, stream>>>(Xbf, WoutT, 1024, nullptr, nullptr, nullptr, out);
}

// Round 14
// 162.654 us; speedup vs baseline: 1.1904x; 1.0819x over previous
//
#include <hip/hip_runtime.h>
#include <hip/hip_bf16.h>

typedef unsigned short u16;
typedef __attribute__((ext_vector_type(8))) short short8;
typedef __attribute__((ext_vector_type(2))) float f32x2;
typedef __attribute__((ext_vector_type(4))) float f32x4;
typedef __attribute__((ext_vector_type(16))) float f32x16;

#define NH 16
#define HD 64
#define SEQ 2048
#define NBATCH 2
#define DM 1024

#define GLOAD_LDS(g, l)                                                              \
  __builtin_amdgcn_global_load_lds((__attribute__((address_space(1))) const void*)(g), \
                                   (__attribute__((address_space(3))) void*)(l), 16, 0, 0)

__device__ __forceinline__ u16 f2bf(float f) {
  __hip_bfloat16 h = __float2bfloat16(f);
  return *reinterpret_cast<u16*>(&h);
}
__device__ __forceinline__ float bf2f(u16 u) {
  union { unsigned int i; float f; } v; v.i = ((unsigned int)u) << 16; return v.f;
}
__device__ __forceinline__ f32x4 mfma16(short8 a, short8 b, f32x4 c) {
  return __builtin_amdgcn_mfma_f32_16x16x32_bf16(a, b, c, 0, 0, 0);
}
__device__ __forceinline__ f32x16 mfma32(short8 a, short8 b, f32x16 c) {
  return __builtin_amdgcn_mfma_f32_32x32x16_bf16(a, b, c, 0, 0, 0);
}

// ---------------- f32 -> bf16 convert (vectorized) ----------------
__global__ void k_convert(const float* __restrict__ src, u16* __restrict__ dst, int n4) {
  int i = blockIdx.x * blockDim.x + threadIdx.x;
  if (i >= n4) return;
  float4 v = reinterpret_cast<const float4*>(src)[i];
  union { u16 h[4]; unsigned long long u; } o;
  o.h[0] = f2bf(v.x); o.h[1] = f2bf(v.y); o.h[2] = f2bf(v.z); o.h[3] = f2bf(v.w);
  reinterpret_cast<unsigned long long*>(dst)[i] = o.u;
}

// ---------------- f32 [R][C] -> bf16 [C][R] transpose ----------------
__global__ void k_transpose(const float* __restrict__ src, u16* __restrict__ dst, int R, int C) {
  __shared__ float t[32][33];
  int c0 = blockIdx.x * 32, r0 = blockIdx.y * 32;
  int tx = threadIdx.x, ty = threadIdx.y;
#pragma unroll
  for (int i = 0; i < 4; ++i)
    t[ty + 8 * i][tx] = src[(size_t)(r0 + ty + 8 * i) * C + c0 + tx];
  __syncthreads();
#pragma unroll
  for (int i = 0; i < 4; ++i)
    dst[(size_t)(c0 + ty + 8 * i) * R + r0 + tx] = f2bf(t[tx][ty + 8 * i]);
}

// ---------------- RoPE sin/cos table: [pos][i] -> (sin, cos) ----------------
__global__ void k_sincos(float2* __restrict__ sc) {
  int idx = blockIdx.x * 256 + threadIdx.x;  // 2048*32
  int p = idx >> 5, i = idx & 31;
  const float l2ts = 0.41524101186092029f;  // log2(10000)/32
  float inv = exp2f(-(float)i * l2ts);      // 10000^(-i/32)
  float arg = (float)p * inv;
  float s, c;
  sincosf(arg, &s, &c);
  sc[idx] = make_float2(s, c);
}

// ---------------- RoPE in-place on Q (scaled 1/8) and K ----------------
// Separate streaming kernel (coalesced uint4 loads): ~7us. Fusing this into
// the GEMM epilogue costs ~45us of uncoalesced segpos/sc gathers — R6 post-mortem.
__global__ void k_rope(u16* __restrict__ Q, u16* __restrict__ K,
                       const int* __restrict__ segpos, const float2* __restrict__ sc) {
  int rid = blockIdx.x * 256 + threadIdx.x;  // 2 * B*H*S rows
  u16* buf = (rid < NBATCH * NH * SEQ) ? Q : K;
  float qs = (rid < NBATCH * NH * SEQ) ? 0.125f : 1.0f;
  int r = rid & (NBATCH * NH * SEQ - 1);
  int b = r >> 15;  // / (NH*SEQ)
  int s = r & (SEQ - 1);
  int pos = segpos[b * SEQ + s];
  const float2* scp = sc + (size_t)pos * 32;
  u16* row = buf + (size_t)r * HD;
  uint4 v[8];
#pragma unroll
  for (int i = 0; i < 8; ++i) v[i] = reinterpret_cast<uint4*>(row)[i];
  u16* e = reinterpret_cast<u16*>(v);
#pragma unroll
  for (int i = 0; i < 32; ++i) {
    float a = bf2f(e[i]), bq = bf2f(e[i + 32]);
    float2 t = scp[i];
    float na = (a * t.y - bq * t.x) * qs;
    float nb = (bq * t.y + a * t.x) * qs;
    e[i] = f2bf(na); e[i + 32] = f2bf(nb);
  }
#pragma unroll
  for (int i = 0; i < 8; ++i) reinterpret_cast<uint4*>(row)[i] = v[i];
}

// ---------------- bf16 MFMA GEMM, 128x128 tile, BK=64, global_load_lds ----------------
// A [M][1024] row-major bf16; Bt [N][1024] row-major bf16 (= B^T).
// R14: T2 XOR-swizzle, both-sides-or-neither form (m104/m201): LDS stays
// linear; the GLOBAL source column and the LDS READ column are both XOR'd
// by the same involution (elem-slot ^= row&7). R13 accounting showed the
// 16-way conflict on fragment reads (row stride 128B = bank period) put
// ~3450 LDS cycles in a 3400-cycle CU-step budget — LDS was the wall.
// After: lanes spread across 8 bank-slots, 2-way = free (m136).
// MODE 0: epilogue scatters in_proj into Q/K [b][h][s][64] and TILED
//         Vt [b][h][kt=s/32][d=64][kv=s%32] (R13).
// MODE 1: plain f32 store to out [M][N].
// XCD-aware block swizzle (T1): grid sizes 768/256 are %8==0 -> bijective.
template <int MODE>
__global__ __launch_bounds__(256) void k_gemm(const u16* __restrict__ A, const u16* __restrict__ Bt,
                                              int N, u16* __restrict__ q, u16* __restrict__ kk,
                                              u16* __restrict__ vt, float* __restrict__ out) {
  __shared__ alignas(16) u16 As[128][64];
  __shared__ alignas(16) u16 Bs[128][64];
  const int K = 1024;
  int tid = threadIdx.x;
  int lane = tid & 63, w = tid >> 6;
  int wr = w >> 1, wc = w & 1;
  int col = lane & 15, grp = lane >> 4;
  int cx = col & 7;  // = row&7 of every fragment row this lane reads
  int bid = blockIdx.y * gridDim.x + blockIdx.x;
  int qq = (gridDim.x * gridDim.y) >> 3;
  int swz = (bid & 7) * qq + (bid >> 3);
  int m0 = (swz / gridDim.x) * 128;
  int n0 = (swz % gridDim.x) * 128;
  // global_load_lds chunk geometry: chunk = 1KB = 8 rows of 64 bf16; lane
  // writes LDS bytes [chunk*1024 + lane*16) -> row chunk*8+(lane>>3).
  // T2 pre-swizzle: source column slot XOR'd with row&7 (= lane>>3).
  int crow = lane >> 3;
  int ccol = ((lane & 7) ^ (lane >> 3)) * 8;
  f32x4 zero4 = {0.f, 0.f, 0.f, 0.f};
  f32x4 acc[4][4];
#pragma unroll
  for (int i = 0; i < 4; ++i)
#pragma unroll
    for (int j = 0; j < 4; ++j) acc[i][j] = zero4;

  for (int k0 = 0; k0 < K; k0 += 64) {
    __syncthreads();  // previous compute done before overwrite
#pragma unroll
    for (int c = 0; c < 4; ++c) {
      int chunk = w * 4 + c;
      int r = chunk * 8 + crow;
      GLOAD_LDS(&A[(size_t)(m0 + r) * K + k0 + ccol], &As[0][0] + chunk * 512);
      GLOAD_LDS(&Bt[(size_t)(n0 + r) * K + k0 + ccol], &Bs[0][0] + chunk * 512);
    }
    __syncthreads();  // vmcnt drained by barrier -> tiles visible
#pragma unroll
    for (int kf = 0; kf < 2; ++kf) {
      short8 af[4], bfr[4];
      int sw = ((kf * 4 + grp) ^ cx) * 8;  // swizzled read column (elems)
#pragma unroll
      for (int i = 0; i < 4; ++i)
        af[i] = *reinterpret_cast<const short8*>(&As[wr * 64 + i * 16 + col][sw]);
#pragma unroll
      for (int i = 0; i < 4; ++i)
        bfr[i] = *reinterpret_cast<const short8*>(&Bs[wc * 64 + i * 16 + col][sw]);
#pragma unroll
      for (int mi = 0; mi < 4; ++mi)
#pragma unroll
        for (int ni = 0; ni < 4; ++ni) acc[mi][ni] = mfma16(af[mi], bfr[ni], acc[mi][ni]);
    }
  }
#pragma unroll
  for (int mi = 0; mi < 4; ++mi)
#pragma unroll
    for (int ni = 0; ni < 4; ++ni)
#pragma unroll
      for (int j = 0; j < 4; ++j) {
        int m = m0 + wr * 64 + mi * 16 + grp * 4 + j;
        int n = n0 + wc * 64 + ni * 16 + col;
        float v = acc[mi][ni][j];
        if (MODE == 0) {
          int b = m >> 11, s = m & 2047;
          int h = n / 192, f = n - h * 192;
          u16 bv = f2bf(v);
          if (f < 64)
            q[(((size_t)(b * NH + h) * SEQ + s) << 6) + f] = bv;
          else if (f < 128)
            kk[(((size_t)(b * NH + h) * SEQ + s) << 6) + (f - 64)] = bv;
          else
            vt[(size_t)(b * NH + h) * (HD * SEQ) + (size_t)(s >> 5) * 2048 +
               (f - 128) * 32 + (s & 31)] = bv;
        } else {
          out[(size_t)m * N + n] = v;
        }
      }
}

// ---------------- flash attention, causal, softcap 50 ----------------
// R9 structure (known-good): 4-wave blocks, grid 1024, uniform-work pairing
// (63-i, i), split-KV x4, serial combine. Packed-f32 softmax (R11). TILED
// Vt layout (R13: V loads hit 32 shared lines/tile instead of 64 distinct
// 4KB-strided lines — attn dropped below the gemm in the profile).
// No prefetch (R8/R12 spilled). 4 waves/SIMD is the occupancy ceiling (R10).
__global__ __launch_bounds__(256, 4) void k_attn(const u16* __restrict__ Q,
                                                 const u16* __restrict__ K,
                                                 const u16* __restrict__ Vt,
                                                 u16* __restrict__ X) {
  int lin = blockIdx.x;          // 0..1023
  int xcd = lin & 7;             // dispatch round-robins XCDs
  int jj = lin >> 3;             // 0..127
  int bh = xcd * 4 + (jj & 3);   // 4 heads per XCD -> K+V 2MB/XCD, L2-resident
  int iq = jj >> 2;              // 0..31
  int tid = threadIdx.x, lane = tid & 63, w = tid >> 6;
  int ql = lane & 31, hi = lane >> 5;
  const u16* Qb = Q + (size_t)bh * SEQ * HD;
  const u16* Kb = K + (size_t)bh * SEQ * HD;
  const u16* Vb = Vt + (size_t)bh * HD * SEQ;
  int b = bh >> 4, h = bh & 15;
  size_t ob = (size_t)b * SEQ * DM + (size_t)h * HD;

  __shared__ float cbuf[64][34];  // combine: 16+16+1 f32 per lane

  const float L2E = 1.4426950408889634f;
  const f32x2 C32 = {-1.9235933878519513e-4f, -1.9235933878519513e-4f};  // -L2E/7500
  const f32x2 C52 = {3.0777494205630686e-8f, 3.0777494205630686e-8f};    // 2*L2E/(15*50^4)
  const f32x2 L2E2 = {L2E, L2E};

  for (int half = 0; half < 2; ++half) {
    int qc = half ? iq : 63 - iq;  // pair sums to 65 tiles -> uniform blocks
    int qbase = qc * 32;

    // Q fragments (B-operand): Q[qbase+ql][d0*16 + hi*8 .. +8]
    short8 qf[4];
#pragma unroll
    for (int d0 = 0; d0 < 4; ++d0)
      qf[d0] = *reinterpret_cast<const short8*>(&Qb[(size_t)(qbase + ql) * HD + d0 * 16 + hi * 8]);

    f32x16 xacc0, xacc1;
#pragma unroll
    for (int r = 0; r < 16; ++r) { xacc0[r] = 0.f; xacc1[r] = 0.f; }
    f32x2 lsum2 = {0.f, 0.f};

    int nkt = qc + 1;  // KV tiles of 32
    for (int kt = w; kt < nkt; kt += 4) {
      int kbase = kt * 32;
      bool diag = (kt == qc);  // wave-uniform

      // K fragments (A-operand): K[kbase+ql][d0*16 + hi*8 .. +8]
      short8 kf[4];
#pragma unroll
      for (int d0 = 0; d0 < 4; ++d0)
        kf[d0] = *reinterpret_cast<const short8*>(
            &Kb[(size_t)(kbase + ql) * HD + d0 * 16 + hi * 8]);

      // S^T[k-rel][q] += K . Q^T over 4 d-chunks
      f32x16 sacc;
#pragma unroll
      for (int r = 0; r < 16; ++r) sacc[r] = 0.f;
#pragma unroll
      for (int d0 = 0; d0 < 4; ++d0) sacc = mfma32(kf[d0], qf[d0], sacc);

      // V fragments from TILED layout: tile base + (dh*32+ql)*32 + c*16 + hi*8
      const u16* Vtile = Vb + (size_t)kt * 2048;
      short8 vf[2][2];
#pragma unroll
      for (int c = 0; c < 2; ++c)
#pragma unroll
        for (int dh = 0; dh < 2; ++dh)
          vf[c][dh] = *reinterpret_cast<const short8*>(
              &Vtile[(dh * 32 + ql) * 32 + c * 16 + hi * 8]);

      // softcap + exp (fixed max 0), PACKED over r-pairs:
      // p = exp2(s*(L2E + t*(C3 + t*C5))), t = s*s  -> v_pk_mul/fma_f32
      float p[16];
#pragma unroll
      for (int r2 = 0; r2 < 8; ++r2) {
        f32x2 s2 = {sacc[2 * r2], sacc[2 * r2 + 1]};
        f32x2 t2 = s2 * s2;
        f32x2 u2 = __builtin_elementwise_fma(t2, C52, C32);
        u2 = __builtin_elementwise_fma(t2, u2, L2E2);
        f32x2 v2 = s2 * u2;
        float p0 = exp2f(v2.x), p1 = exp2f(v2.y);
        if (diag) {
          int r = 2 * r2;
          int kpos0 = kbase + (r & 3) + 8 * (r >> 2) + 4 * hi;
          int kpos1 = kbase + ((r + 1) & 3) + 8 * ((r + 1) >> 2) + 4 * hi;
          if (kpos0 > qbase + ql) p0 = 0.f;
          if (kpos1 > qbase + ql) p1 = 0.f;
        }
        p[2 * r2] = p0;
        p[2 * r2 + 1] = p1;
        lsum2 += (f32x2){p0, p1};
      }

      // pack P rows into PV A-fragments: chunk c = k-rel [16c, 16c+16)
      short8 pfrag[2];
#pragma unroll
      for (int c = 0; c < 2; ++c) {
        unsigned int a0, a1, b0, b1;
        asm("v_cvt_pk_bf16_f32 %0, %1, %2" : "=v"(a0) : "v"(p[8 * c + 0]), "v"(p[8 * c + 1]));
        asm("v_cvt_pk_bf16_f32 %0, %1, %2" : "=v"(a1) : "v"(p[8 * c + 2]), "v"(p[8 * c + 3]));
        asm("v_cvt_pk_bf16_f32 %0, %1, %2" : "=v"(b0) : "v"(p[8 * c + 4]), "v"(p[8 * c + 5]));
        asm("v_cvt_pk_bf16_f32 %0, %1, %2" : "=v"(b1) : "v"(p[8 * c + 6]), "v"(p[8 * c + 7]));
        // dst' = {dst.lo, src.lo}; src' = {dst.hi, src.hi}
        asm("v_permlane32_swap_b32 %0, %1" : "+v"(a0), "+v"(b0));
        asm("v_permlane32_swap_b32 %0, %1" : "+v"(a1), "+v"(b1));
        union { unsigned int u[4]; short8 s8; } pk;
        pk.u[0] = a0; pk.u[1] = a1; pk.u[2] = b0; pk.u[3] = b1;
        pfrag[c] = pk.s8;
      }

      // PV: X[q][d] += P . V  (two d-halves)
#pragma unroll
      for (int c = 0; c < 2; ++c) {
        xacc0 = mfma32(pfrag[c], vf[c][0], xacc0);
        xacc1 = mfma32(pfrag[c], vf[c][1], xacc1);
      }
    }
    float lsum = lsum2.x + lsum2.y;

    // ---- combine the 4 waves' partials (plain sums; M=0 softmax) ----
    __syncthreads();
    for (int src = 1; src < 4; ++src) {
      if (w == src) {
#pragma unroll
        for (int r = 0; r < 16; ++r) {
          if (src == 1) { cbuf[lane][r] = xacc0[r]; cbuf[lane][16 + r] = xacc1[r]; }
          else { cbuf[lane][r] += xacc0[r]; cbuf[lane][16 + r] += xacc1[r]; }
        }
        if (src == 1) cbuf[lane][32] = lsum; else cbuf[lane][32] += lsum;
      }
      __syncthreads();
    }

    if (w == 0) {
#pragma unroll
      for (int r = 0; r < 16; ++r) { xacc0[r] += cbuf[lane][r]; xacc1[r] += cbuf[lane][16 + r]; }
      lsum += cbuf[lane][32];
      // lanes q and q+32 hold the two k-half partials of row q
      lsum += __shfl_xor(lsum, 32, 64);
      float rinv = __builtin_amdgcn_rcpf(lsum);  // valid for q = ql on every lane

#pragma unroll
      for (int r = 0; r < 16; ++r) {
        int qrel = (r & 3) + 8 * (r >> 2) + 4 * hi;
        float rv = __shfl(rinv, qrel, 64);
        size_t row = ob + (size_t)(qbase + qrel) * DM;
        X[row + ql] = f2bf(xacc0[r] * rv);
        X[row + 32 + ql] = f2bf(xacc1[r] * rv);
      }
    }
    __syncthreads();  // cbuf safe for reuse by next half
  }
}

extern "C" void kernel_launch(void* const* d_in, const int* in_sizes, int n_in,
                              void* d_out, int out_size, void* d_ws, size_t ws_size,
                              hipStream_t stream) {
  const float* inputs = (const float*)d_in[0];
  const int* segpos = (const int*)d_in[1];
  // d_in[2] = mask: causal tril, known analytically — unused.
  const float* w_in = (const float*)d_in[3];
  const float* w_out = (const float*)d_in[4];
  float* out = (float*)d_out;
  char* ws = (char*)d_ws;

  size_t o = 0;
  u16* Xbf = (u16*)(ws + o); o += (size_t)4096 * 1024 * 2;   // inputs bf16; reused as attn output
  u16* WinT = (u16*)(ws + o); o += (size_t)3072 * 1024 * 2;  // w_in^T bf16
  u16* WoutT = (u16*)(ws + o); o += (size_t)1024 * 1024 * 2; // w_out^T bf16
  u16* Qb = (u16*)(ws + o); o += (size_t)NBATCH * NH * SEQ * HD * 2;
  u16* Kb = (u16*)(ws + o); o += (size_t)NBATCH * NH * SEQ * HD * 2;
  u16* Vt = (u16*)(ws + o); o += (size_t)NBATCH * NH * HD * SEQ * 2;
  float2* SC = (float2*)(ws + o); o += (size_t)SEQ * 32 * sizeof(float2);

  k_convert<<<4096, 256, 0, stream>>>(inputs, Xbf, 1048576);
  k_transpose<<<dim3(96, 32), dim3(32, 8), 0, stream>>>(w_in, WinT, 1024, 3072);
  k_transpose<<<dim3(32, 32), dim3(32, 8), 0, stream>>>(w_out, WoutT, 1024, 1024);
  k_sincos<<<256, 256, 0, stream>>>(SC);
  k_gemm<0><<<dim3(24, 32), 256, 0, stream>>>(Xbf, WinT, 3072, Qb, Kb, Vt, nullptr);
  k_rope<<<512, 256, 0, stream>>>(Qb, Kb, segpos, SC);
  k_attn<<<1024, 256, 0, stream>>>(Qb, Kb, Vt, Xbf);
  k_gemm<1><<<dim3(8, 32), 256, 0, stream>>>(Xbf, WoutT, 1024, nullptr, nullptr, nullptr, out);
}

// Round 15
// 157.287 us; speedup vs baseline: 1.2310x; 1.0341x over previous
//
#include <hip/hip_runtime.h>
#include <hip/hip_bf16.h>

typedef unsigned short u16;
typedef __attribute__((ext_vector_type(8))) short short8;
typedef __attribute__((ext_vector_type(2))) float f32x2;
typedef __attribute__((ext_vector_type(4))) float f32x4;
typedef __attribute__((ext_vector_type(16))) float f32x16;

#define NH 16
#define HD 64
#define SEQ 2048
#define NBATCH 2
#define DM 1024

#define GLOAD_LDS(g, l)                                                              \
  __builtin_amdgcn_global_load_lds((__attribute__((address_space(1))) const void*)(g), \
                                   (__attribute__((address_space(3))) void*)(l), 16, 0, 0)

__device__ __forceinline__ u16 f2bf(float f) {
  __hip_bfloat16 h = __float2bfloat16(f);
  return *reinterpret_cast<u16*>(&h);
}
__device__ __forceinline__ float bf2f(u16 u) {
  union { unsigned int i; float f; } v; v.i = ((unsigned int)u) << 16; return v.f;
}
__device__ __forceinline__ f32x4 mfma16(short8 a, short8 b, f32x4 c) {
  return __builtin_amdgcn_mfma_f32_16x16x32_bf16(a, b, c, 0, 0, 0);
}
__device__ __forceinline__ f32x16 mfma32(short8 a, short8 b, f32x16 c) {
  return __builtin_amdgcn_mfma_f32_32x32x16_bf16(a, b, c, 0, 0, 0);
}

// ---------------- fused prep: convert | transpose(w_in) | transpose(w_out) | sincos ----
// R15: 4 independent memory-bound kernels -> 1 dispatch (sectioned by blockIdx).
// Saves 3 launch gaps and lets the streams overlap.
__global__ __launch_bounds__(256) void k_prep(const float* __restrict__ inputs,
                                              u16* __restrict__ Xbf,
                                              const float* __restrict__ w_in,
                                              u16* __restrict__ WinT,
                                              const float* __restrict__ w_out,
                                              u16* __restrict__ WoutT,
                                              float2* __restrict__ SC) {
  __shared__ float t[32][33];
  int blk = blockIdx.x, tid = threadIdx.x;
  if (blk < 4096) {
    // f32 -> bf16 convert (4M floats as 1M float4)
    int i = blk * 256 + tid;
    float4 v = reinterpret_cast<const float4*>(inputs)[i];
    union { u16 h[4]; unsigned long long u; } o;
    o.h[0] = f2bf(v.x); o.h[1] = f2bf(v.y); o.h[2] = f2bf(v.z); o.h[3] = f2bf(v.w);
    reinterpret_cast<unsigned long long*>(Xbf)[i] = o.u;
  } else if (blk < 4096 + 3072 + 1024) {
    // f32 [R][C] -> bf16 [C][R] transpose (w_in: 1024x3072; w_out: 1024x1024)
    const float* src; u16* dst; int C, bx, by;
    if (blk < 4096 + 3072) {
      int b2 = blk - 4096; src = w_in; dst = WinT; C = 3072; bx = b2 % 96; by = b2 / 96;
    } else {
      int b2 = blk - (4096 + 3072); src = w_out; dst = WoutT; C = 1024; bx = b2 & 31; by = b2 >> 5;
    }
    const int R = 1024;
    int c0 = bx * 32, r0 = by * 32;
    int tx = tid & 31, ty = tid >> 5;
#pragma unroll
    for (int i = 0; i < 4; ++i)
      t[ty + 8 * i][tx] = src[(size_t)(r0 + ty + 8 * i) * C + c0 + tx];
    __syncthreads();
#pragma unroll
    for (int i = 0; i < 4; ++i)
      dst[(size_t)(c0 + ty + 8 * i) * R + r0 + tx] = f2bf(t[tx][ty + 8 * i]);
  } else {
    // RoPE sin/cos table: [pos][i] -> (sin, cos), 2048*32 entries
    int idx = (blk - 8192) * 256 + tid;
    int p = idx >> 5, i = idx & 31;
    const float l2ts = 0.41524101186092029f;  // log2(10000)/32
    float inv = exp2f(-(float)i * l2ts);      // 10000^(-i/32)
    float arg = (float)p * inv;
    float s, c;
    sincosf(arg, &s, &c);
    SC[idx] = make_float2(s, c);
  }
}

// ---------------- RoPE in-place on Q (scaled 1/8) and K ----------------
// Separate streaming kernel (coalesced uint4 loads): ~7us. Fusing this into
// the GEMM epilogue costs ~45us of uncoalesced segpos/sc gathers — R6 post-mortem.
__global__ void k_rope(u16* __restrict__ Q, u16* __restrict__ K,
                       const int* __restrict__ segpos, const float2* __restrict__ sc) {
  int rid = blockIdx.x * 256 + threadIdx.x;  // 2 * B*H*S rows
  u16* buf = (rid < NBATCH * NH * SEQ) ? Q : K;
  float qs = (rid < NBATCH * NH * SEQ) ? 0.125f : 1.0f;
  int r = rid & (NBATCH * NH * SEQ - 1);
  int b = r >> 15;  // / (NH*SEQ)
  int s = r & (SEQ - 1);
  int pos = segpos[b * SEQ + s];
  const float2* scp = sc + (size_t)pos * 32;
  u16* row = buf + (size_t)r * HD;
  uint4 v[8];
#pragma unroll
  for (int i = 0; i < 8; ++i) v[i] = reinterpret_cast<uint4*>(row)[i];
  u16* e = reinterpret_cast<u16*>(v);
#pragma unroll
  for (int i = 0; i < 32; ++i) {
    float a = bf2f(e[i]), bq = bf2f(e[i + 32]);
    float2 t = scp[i];
    float na = (a * t.y - bq * t.x) * qs;
    float nb = (bq * t.y + a * t.x) * qs;
    e[i] = f2bf(na); e[i + 32] = f2bf(nb);
  }
#pragma unroll
  for (int i = 0; i < 8; ++i) reinterpret_cast<uint4*>(row)[i] = v[i];
}

// ---------------- bf16 MFMA GEMM, 128x128 tile, BK=64, global_load_lds ----------------
// A [M][1024] row-major bf16; Bt [N][1024] row-major bf16 (= B^T).
// T2 XOR-swizzle, both-sides-or-neither form (R14: conflicts 9.4M -> ~0,
// gemm<0> 68 -> <62us): LDS linear; global source column and LDS read column
// both XOR'd by the same involution (elem-slot ^= row&7).
// MODE 0: epilogue scatters in_proj into Q/K [b][h][s][64] and TILED
//         Vt [b][h][kt=s/32][d=64][kv=s%32] (R13).
// MODE 1: plain f32 store to out [M][N].
// XCD-aware block swizzle (T1): grid sizes 768/256 are %8==0 -> bijective.
template <int MODE>
__global__ __launch_bounds__(256) void k_gemm(const u16* __restrict__ A, const u16* __restrict__ Bt,
                                              int N, u16* __restrict__ q, u16* __restrict__ kk,
                                              u16* __restrict__ vt, float* __restrict__ out) {
  __shared__ alignas(16) u16 As[128][64];
  __shared__ alignas(16) u16 Bs[128][64];
  const int K = 1024;
  int tid = threadIdx.x;
  int lane = tid & 63, w = tid >> 6;
  int wr = w >> 1, wc = w & 1;
  int col = lane & 15, grp = lane >> 4;
  int cx = col & 7;  // = row&7 of every fragment row this lane reads
  int bid = blockIdx.y * gridDim.x + blockIdx.x;
  int qq = (gridDim.x * gridDim.y) >> 3;
  int swz = (bid & 7) * qq + (bid >> 3);
  int m0 = (swz / gridDim.x) * 128;
  int n0 = (swz % gridDim.x) * 128;
  // global_load_lds chunk geometry: chunk = 1KB = 8 rows of 64 bf16; lane
  // writes LDS bytes [chunk*1024 + lane*16) -> row chunk*8+(lane>>3).
  // T2 pre-swizzle: source column slot XOR'd with row&7 (= lane>>3).
  int crow = lane >> 3;
  int ccol = ((lane & 7) ^ (lane >> 3)) * 8;
  f32x4 zero4 = {0.f, 0.f, 0.f, 0.f};
  f32x4 acc[4][4];
#pragma unroll
  for (int i = 0; i < 4; ++i)
#pragma unroll
    for (int j = 0; j < 4; ++j) acc[i][j] = zero4;

  for (int k0 = 0; k0 < K; k0 += 64) {
    __syncthreads();  // previous compute done before overwrite
#pragma unroll
    for (int c = 0; c < 4; ++c) {
      int chunk = w * 4 + c;
      int r = chunk * 8 + crow;
      GLOAD_LDS(&A[(size_t)(m0 + r) * K + k0 + ccol], &As[0][0] + chunk * 512);
      GLOAD_LDS(&Bt[(size_t)(n0 + r) * K + k0 + ccol], &Bs[0][0] + chunk * 512);
    }
    __syncthreads();  // vmcnt drained by barrier -> tiles visible
#pragma unroll
    for (int kf = 0; kf < 2; ++kf) {
      short8 af[4], bfr[4];
      int sw = ((kf * 4 + grp) ^ cx) * 8;  // swizzled read column (elems)
#pragma unroll
      for (int i = 0; i < 4; ++i)
        af[i] = *reinterpret_cast<const short8*>(&As[wr * 64 + i * 16 + col][sw]);
#pragma unroll
      for (int i = 0; i < 4; ++i)
        bfr[i] = *reinterpret_cast<const short8*>(&Bs[wc * 64 + i * 16 + col][sw]);
#pragma unroll
      for (int mi = 0; mi < 4; ++mi)
#pragma unroll
        for (int ni = 0; ni < 4; ++ni) acc[mi][ni] = mfma16(af[mi], bfr[ni], acc[mi][ni]);
    }
  }
#pragma unroll
  for (int mi = 0; mi < 4; ++mi)
#pragma unroll
    for (int ni = 0; ni < 4; ++ni)
#pragma unroll
      for (int j = 0; j < 4; ++j) {
        int m = m0 + wr * 64 + mi * 16 + grp * 4 + j;
        int n = n0 + wc * 64 + ni * 16 + col;
        float v = acc[mi][ni][j];
        if (MODE == 0) {
          int b = m >> 11, s = m & 2047;
          int h = n / 192, f = n - h * 192;
          u16 bv = f2bf(v);
          if (f < 64)
            q[(((size_t)(b * NH + h) * SEQ + s) << 6) + f] = bv;
          else if (f < 128)
            kk[(((size_t)(b * NH + h) * SEQ + s) << 6) + (f - 64)] = bv;
          else
            vt[(size_t)(b * NH + h) * (HD * SEQ) + (size_t)(s >> 5) * 2048 +
               (f - 128) * 32 + (s & 31)] = bv;
        } else {
          out[(size_t)m * N + n] = v;
        }
      }
}

// ---------------- flash attention, causal, softcap 50 ----------------
// R9 structure (known-good): 4-wave blocks, grid 1024, uniform-work pairing
// (63-i, i), split-KV x4, serial combine. Packed-f32 softmax (R11). TILED
// Vt layout (R13). R15: T5 s_setprio(1) around the QK and PV MFMA clusters —
// this loop is barrier-free with phase-staggered waves (m191 regime, +4-7%),
// unlike R10 where setprio was confounded with a spill.
// No prefetch (R8/R12 spilled). 4 waves/SIMD is the occupancy ceiling (R10).
__global__ __launch_bounds__(256, 4) void k_attn(const u16* __restrict__ Q,
                                                 const u16* __restrict__ K,
                                                 const u16* __restrict__ Vt,
                                                 u16* __restrict__ X) {
  int lin = blockIdx.x;          // 0..1023
  int xcd = lin & 7;             // dispatch round-robins XCDs
  int jj = lin >> 3;             // 0..127
  int bh = xcd * 4 + (jj & 3);   // 4 heads per XCD -> K+V 2MB/XCD, L2-resident
  int iq = jj >> 2;              // 0..31
  int tid = threadIdx.x, lane = tid & 63, w = tid >> 6;
  int ql = lane & 31, hi = lane >> 5;
  const u16* Qb = Q + (size_t)bh * SEQ * HD;
  const u16* Kb = K + (size_t)bh * SEQ * HD;
  const u16* Vb = Vt + (size_t)bh * HD * SEQ;
  int b = bh >> 4, h = bh & 15;
  size_t ob = (size_t)b * SEQ * DM + (size_t)h * HD;

  __shared__ float cbuf[64][34];  // combine: 16+16+1 f32 per lane

  const float L2E = 1.4426950408889634f;
  const f32x2 C32 = {-1.9235933878519513e-4f, -1.9235933878519513e-4f};  // -L2E/7500
  const f32x2 C52 = {3.0777494205630686e-8f, 3.0777494205630686e-8f};    // 2*L2E/(15*50^4)
  const f32x2 L2E2 = {L2E, L2E};

  for (int half = 0; half < 2; ++half) {
    int qc = half ? iq : 63 - iq;  // pair sums to 65 tiles -> uniform blocks
    int qbase = qc * 32;

    // Q fragments (B-operand): Q[qbase+ql][d0*16 + hi*8 .. +8]
    short8 qf[4];
#pragma unroll
    for (int d0 = 0; d0 < 4; ++d0)
      qf[d0] = *reinterpret_cast<const short8*>(&Qb[(size_t)(qbase + ql) * HD + d0 * 16 + hi * 8]);

    f32x16 xacc0, xacc1;
#pragma unroll
    for (int r = 0; r < 16; ++r) { xacc0[r] = 0.f; xacc1[r] = 0.f; }
    f32x2 lsum2 = {0.f, 0.f};

    int nkt = qc + 1;  // KV tiles of 32
    for (int kt = w; kt < nkt; kt += 4) {
      int kbase = kt * 32;
      bool diag = (kt == qc);  // wave-uniform

      // K fragments (A-operand): K[kbase+ql][d0*16 + hi*8 .. +8]
      short8 kf[4];
#pragma unroll
      for (int d0 = 0; d0 < 4; ++d0)
        kf[d0] = *reinterpret_cast<const short8*>(
            &Kb[(size_t)(kbase + ql) * HD + d0 * 16 + hi * 8]);

      // S^T[k-rel][q] += K . Q^T over 4 d-chunks
      f32x16 sacc;
#pragma unroll
      for (int r = 0; r < 16; ++r) sacc[r] = 0.f;
      __builtin_amdgcn_s_setprio(1);
#pragma unroll
      for (int d0 = 0; d0 < 4; ++d0) sacc = mfma32(kf[d0], qf[d0], sacc);
      __builtin_amdgcn_s_setprio(0);

      // V fragments from TILED layout: tile base + (dh*32+ql)*32 + c*16 + hi*8
      const u16* Vtile = Vb + (size_t)kt * 2048;
      short8 vf[2][2];
#pragma unroll
      for (int c = 0; c < 2; ++c)
#pragma unroll
        for (int dh = 0; dh < 2; ++dh)
          vf[c][dh] = *reinterpret_cast<const short8*>(
              &Vtile[(dh * 32 + ql) * 32 + c * 16 + hi * 8]);

      // softcap + exp (fixed max 0), PACKED over r-pairs:
      // p = exp2(s*(L2E + t*(C3 + t*C5))), t = s*s  -> v_pk_mul/fma_f32
      float p[16];
#pragma unroll
      for (int r2 = 0; r2 < 8; ++r2) {
        f32x2 s2 = {sacc[2 * r2], sacc[2 * r2 + 1]};
        f32x2 t2 = s2 * s2;
        f32x2 u2 = __builtin_elementwise_fma(t2, C52, C32);
        u2 = __builtin_elementwise_fma(t2, u2, L2E2);
        f32x2 v2 = s2 * u2;
        float p0 = exp2f(v2.x), p1 = exp2f(v2.y);
        if (diag) {
          int r = 2 * r2;
          int kpos0 = kbase + (r & 3) + 8 * (r >> 2) + 4 * hi;
          int kpos1 = kbase + ((r + 1) & 3) + 8 * ((r + 1) >> 2) + 4 * hi;
          if (kpos0 > qbase + ql) p0 = 0.f;
          if (kpos1 > qbase + ql) p1 = 0.f;
        }
        p[2 * r2] = p0;
        p[2 * r2 + 1] = p1;
        lsum2 += (f32x2){p0, p1};
      }

      // pack P rows into PV A-fragments: chunk c = k-rel [16c, 16c+16)
      short8 pfrag[2];
#pragma unroll
      for (int c = 0; c < 2; ++c) {
        unsigned int a0, a1, b0, b1;
        asm("v_cvt_pk_bf16_f32 %0, %1, %2" : "=v"(a0) : "v"(p[8 * c + 0]), "v"(p[8 * c + 1]));
        asm("v_cvt_pk_bf16_f32 %0, %1, %2" : "=v"(a1) : "v"(p[8 * c + 2]), "v"(p[8 * c + 3]));
        asm("v_cvt_pk_bf16_f32 %0, %1, %2" : "=v"(b0) : "v"(p[8 * c + 4]), "v"(p[8 * c + 5]));
        asm("v_cvt_pk_bf16_f32 %0, %1, %2" : "=v"(b1) : "v"(p[8 * c + 6]), "v"(p[8 * c + 7]));
        // dst' = {dst.lo, src.lo}; src' = {dst.hi, src.hi}
        asm("v_permlane32_swap_b32 %0, %1" : "+v"(a0), "+v"(b0));
        asm("v_permlane32_swap_b32 %0, %1" : "+v"(a1), "+v"(b1));
        union { unsigned int u[4]; short8 s8; } pk;
        pk.u[0] = a0; pk.u[1] = a1; pk.u[2] = b0; pk.u[3] = b1;
        pfrag[c] = pk.s8;
      }

      // PV: X[q][d] += P . V  (two d-halves)
      __builtin_amdgcn_s_setprio(1);
#pragma unroll
      for (int c = 0; c < 2; ++c) {
        xacc0 = mfma32(pfrag[c], vf[c][0], xacc0);
        xacc1 = mfma32(pfrag[c], vf[c][1], xacc1);
      }
      __builtin_amdgcn_s_setprio(0);
    }
    float lsum = lsum2.x + lsum2.y;

    // ---- combine the 4 waves' partials (plain sums; M=0 softmax) ----
    __syncthreads();
    for (int src = 1; src < 4; ++src) {
      if (w == src) {
#pragma unroll
        for (int r = 0; r < 16; ++r) {
          if (src == 1) { cbuf[lane][r] = xacc0[r]; cbuf[lane][16 + r] = xacc1[r]; }
          else { cbuf[lane][r] += xacc0[r]; cbuf[lane][16 + r] += xacc1[r]; }
        }
        if (src == 1) cbuf[lane][32] = lsum; else cbuf[lane][32] += lsum;
      }
      __syncthreads();
    }

    if (w == 0) {
#pragma unroll
      for (int r = 0; r < 16; ++r) { xacc0[r] += cbuf[lane][r]; xacc1[r] += cbuf[lane][16 + r]; }
      lsum += cbuf[lane][32];
      // lanes q and q+32 hold the two k-half partials of row q
      lsum += __shfl_xor(lsum, 32, 64);
      float rinv = __builtin_amdgcn_rcpf(lsum);  // valid for q = ql on every lane

#pragma unroll
      for (int r = 0; r < 16; ++r) {
        int qrel = (r & 3) + 8 * (r >> 2) + 4 * hi;
        float rv = __shfl(rinv, qrel, 64);
        size_t row = ob + (size_t)(qbase + qrel) * DM;
        X[row + ql] = f2bf(xacc0[r] * rv);
        X[row + 32 + ql] = f2bf(xacc1[r] * rv);
      }
    }
    __syncthreads();  // cbuf safe for reuse by next half
  }
}

extern "C" void kernel_launch(void* const* d_in, const int* in_sizes, int n_in,
                              void* d_out, int out_size, void* d_ws, size_t ws_size,
                              hipStream_t stream) {
  const float* inputs = (const float*)d_in[0];
  const int* segpos = (const int*)d_in[1];
  // d_in[2] = mask: causal tril, known analytically — unused.
  const float* w_in = (const float*)d_in[3];
  const float* w_out = (const float*)d_in[4];
  float* out = (float*)d_out;
  char* ws = (char*)d_ws;

  size_t o = 0;
  u16* Xbf = (u16*)(ws + o); o += (size_t)4096 * 1024 * 2;   // inputs bf16; reused as attn output
  u16* WinT = (u16*)(ws + o); o += (size_t)3072 * 1024 * 2;  // w_in^T bf16
  u16* WoutT = (u16*)(ws + o); o += (size_t)1024 * 1024 * 2; // w_out^T bf16
  u16* Qb = (u16*)(ws + o); o += (size_t)NBATCH * NH * SEQ * HD * 2;
  u16* Kb = (u16*)(ws + o); o += (size_t)NBATCH * NH * SEQ * HD * 2;
  u16* Vt = (u16*)(ws + o); o += (size_t)NBATCH * NH * HD * SEQ * 2;
  float2* SC = (float2*)(ws + o); o += (size_t)SEQ * 32 * sizeof(float2);

  k_prep<<<8448, 256, 0, stream>>>(inputs, Xbf, w_in, WinT, w_out, WoutT, SC);
  k_gemm<0><<<dim3(24, 32), 256, 0, stream>>>(Xbf, WinT, 3072, Qb, Kb, Vt, nullptr);
  k_rope<<<512, 256, 0, stream>>>(Qb, Kb, segpos, SC);
  k_attn<<<1024, 256, 0, stream>>>(Qb, Kb, Vt, Xbf);
  k_gemm<1><<<dim3(8, 32), 256, 0, stream>>>(Xbf, WoutT, 1024, nullptr, nullptr, nullptr, out);
}

// Round 16
// 155.214 us; speedup vs baseline: 1.2474x; 1.0134x over previous
//
#include <hip/hip_runtime.h>
#include <hip/hip_bf16.h>

typedef unsigned short u16;
typedef __attribute__((ext_vector_type(8))) short short8;
typedef __attribute__((ext_vector_type(2))) float f32x2;
typedef __attribute__((ext_vector_type(4))) float f32x4;
typedef __attribute__((ext_vector_type(16))) float f32x16;

#define NH 16
#define HD 64
#define SEQ 2048
#define NBATCH 2
#define DM 1024

#define GLOAD_LDS(g, l)                                                              \
  __builtin_amdgcn_global_load_lds((__attribute__((address_space(1))) const void*)(g), \
                                   (__attribute__((address_space(3))) void*)(l), 16, 0, 0)

__device__ __forceinline__ u16 f2bf(float f) {
  __hip_bfloat16 h = __float2bfloat16(f);
  return *reinterpret_cast<u16*>(&h);
}
__device__ __forceinline__ float bf2f(u16 u) {
  union { unsigned int i; float f; } v; v.i = ((unsigned int)u) << 16; return v.f;
}
__device__ __forceinline__ f32x4 mfma16(short8 a, short8 b, f32x4 c) {
  return __builtin_amdgcn_mfma_f32_16x16x32_bf16(a, b, c, 0, 0, 0);
}
__device__ __forceinline__ f32x16 mfma32(short8 a, short8 b, f32x16 c) {
  return __builtin_amdgcn_mfma_f32_32x32x16_bf16(a, b, c, 0, 0, 0);
}

// ---------------- fused prep: convert | transpose(w_in) | transpose(w_out) | sincos ----
// R15: 4 independent memory-bound kernels -> 1 dispatch (sectioned by blockIdx).
__global__ __launch_bounds__(256) void k_prep(const float* __restrict__ inputs,
                                              u16* __restrict__ Xbf,
                                              const float* __restrict__ w_in,
                                              u16* __restrict__ WinT,
                                              const float* __restrict__ w_out,
                                              u16* __restrict__ WoutT,
                                              float2* __restrict__ SC) {
  __shared__ float t[32][33];
  int blk = blockIdx.x, tid = threadIdx.x;
  if (blk < 4096) {
    // f32 -> bf16 convert (4M floats as 1M float4)
    int i = blk * 256 + tid;
    float4 v = reinterpret_cast<const float4*>(inputs)[i];
    union { u16 h[4]; unsigned long long u; } o;
    o.h[0] = f2bf(v.x); o.h[1] = f2bf(v.y); o.h[2] = f2bf(v.z); o.h[3] = f2bf(v.w);
    reinterpret_cast<unsigned long long*>(Xbf)[i] = o.u;
  } else if (blk < 4096 + 3072 + 1024) {
    // f32 [R][C] -> bf16 [C][R] transpose (w_in: 1024x3072; w_out: 1024x1024)
    const float* src; u16* dst; int C, bx, by;
    if (blk < 4096 + 3072) {
      int b2 = blk - 4096; src = w_in; dst = WinT; C = 3072; bx = b2 % 96; by = b2 / 96;
    } else {
      int b2 = blk - (4096 + 3072); src = w_out; dst = WoutT; C = 1024; bx = b2 & 31; by = b2 >> 5;
    }
    const int R = 1024;
    int c0 = bx * 32, r0 = by * 32;
    int tx = tid & 31, ty = tid >> 5;
#pragma unroll
    for (int i = 0; i < 4; ++i)
      t[ty + 8 * i][tx] = src[(size_t)(r0 + ty + 8 * i) * C + c0 + tx];
    __syncthreads();
#pragma unroll
    for (int i = 0; i < 4; ++i)
      dst[(size_t)(c0 + ty + 8 * i) * R + r0 + tx] = f2bf(t[tx][ty + 8 * i]);
  } else {
    // RoPE sin/cos table: [pos][i] -> (sin, cos), 2048*32 entries
    int idx = (blk - 8192) * 256 + tid;
    int p = idx >> 5, i = idx & 31;
    const float l2ts = 0.41524101186092029f;  // log2(10000)/32
    float inv = exp2f(-(float)i * l2ts);      // 10000^(-i/32)
    float arg = (float)p * inv;
    float s, c;
    sincosf(arg, &s, &c);
    SC[idx] = make_float2(s, c);
  }
}

// ---------------- RoPE in-place on Q (scaled 1/8) and K ----------------
// Separate streaming kernel (coalesced uint4 loads): ~7us. Fusing this into
// the GEMM epilogue costs ~45us of uncoalesced segpos/sc gathers — R6 post-mortem.
__global__ void k_rope(u16* __restrict__ Q, u16* __restrict__ K,
                       const int* __restrict__ segpos, const float2* __restrict__ sc) {
  int rid = blockIdx.x * 256 + threadIdx.x;  // 2 * B*H*S rows
  u16* buf = (rid < NBATCH * NH * SEQ) ? Q : K;
  float qs = (rid < NBATCH * NH * SEQ) ? 0.125f : 1.0f;
  int r = rid & (NBATCH * NH * SEQ - 1);
  int b = r >> 15;  // / (NH*SEQ)
  int s = r & (SEQ - 1);
  int pos = segpos[b * SEQ + s];
  const float2* scp = sc + (size_t)pos * 32;
  u16* row = buf + (size_t)r * HD;
  uint4 v[8];
#pragma unroll
  for (int i = 0; i < 8; ++i) v[i] = reinterpret_cast<uint4*>(row)[i];
  u16* e = reinterpret_cast<u16*>(v);
#pragma unroll
  for (int i = 0; i < 32; ++i) {
    float a = bf2f(e[i]), bq = bf2f(e[i + 32]);
    float2 t = scp[i];
    float na = (a * t.y - bq * t.x) * qs;
    float nb = (bq * t.y + a * t.x) * qs;
    e[i] = f2bf(na); e[i + 32] = f2bf(nb);
  }
#pragma unroll
  for (int i = 0; i < 8; ++i) reinterpret_cast<uint4*>(row)[i] = v[i];
}

// ---------------- bf16 MFMA GEMM, 128x128 tile, BK=64, global_load_lds ----------------
// A [M][1024] row-major bf16; Bt [N][1024] row-major bf16 (= B^T).
// T2 XOR-swizzle, both-sides-or-neither form (R14: conflicts 9.4M -> ~0,
// gemm<0> 68 -> <62us): LDS linear; global source column and LDS read column
// both XOR'd by the same involution (elem-slot ^= row&7).
// MODE 0: epilogue scatters in_proj into Q/K [b][h][s][64] and TILED
//         Vt [b][h][kt=s/32][d=64][kv=s%32] (R13).
// MODE 1: plain f32 store to out [M][N].
// XCD-aware block swizzle (T1): grid sizes 768/256 are %8==0 -> bijective.
template <int MODE>
__global__ __launch_bounds__(256) void k_gemm(const u16* __restrict__ A, const u16* __restrict__ Bt,
                                              int N, u16* __restrict__ q, u16* __restrict__ kk,
                                              u16* __restrict__ vt, float* __restrict__ out) {
  __shared__ alignas(16) u16 As[128][64];
  __shared__ alignas(16) u16 Bs[128][64];
  const int K = 1024;
  int tid = threadIdx.x;
  int lane = tid & 63, w = tid >> 6;
  int wr = w >> 1, wc = w & 1;
  int col = lane & 15, grp = lane >> 4;
  int cx = col & 7;  // = row&7 of every fragment row this lane reads
  int bid = blockIdx.y * gridDim.x + blockIdx.x;
  int qq = (gridDim.x * gridDim.y) >> 3;
  int swz = (bid & 7) * qq + (bid >> 3);
  int m0 = (swz / gridDim.x) * 128;
  int n0 = (swz % gridDim.x) * 128;
  // global_load_lds chunk geometry: chunk = 1KB = 8 rows of 64 bf16; lane
  // writes LDS bytes [chunk*1024 + lane*16) -> row chunk*8+(lane>>3).
  // T2 pre-swizzle: source column slot XOR'd with row&7 (= lane>>3).
  int crow = lane >> 3;
  int ccol = ((lane & 7) ^ (lane >> 3)) * 8;
  f32x4 zero4 = {0.f, 0.f, 0.f, 0.f};
  f32x4 acc[4][4];
#pragma unroll
  for (int i = 0; i < 4; ++i)
#pragma unroll
    for (int j = 0; j < 4; ++j) acc[i][j] = zero4;

  for (int k0 = 0; k0 < K; k0 += 64) {
    __syncthreads();  // previous compute done before overwrite
#pragma unroll
    for (int c = 0; c < 4; ++c) {
      int chunk = w * 4 + c;
      int r = chunk * 8 + crow;
      GLOAD_LDS(&A[(size_t)(m0 + r) * K + k0 + ccol], &As[0][0] + chunk * 512);
      GLOAD_LDS(&Bt[(size_t)(n0 + r) * K + k0 + ccol], &Bs[0][0] + chunk * 512);
    }
    __syncthreads();  // vmcnt drained by barrier -> tiles visible
#pragma unroll
    for (int kf = 0; kf < 2; ++kf) {
      short8 af[4], bfr[4];
      int sw = ((kf * 4 + grp) ^ cx) * 8;  // swizzled read column (elems)
#pragma unroll
      for (int i = 0; i < 4; ++i)
        af[i] = *reinterpret_cast<const short8*>(&As[wr * 64 + i * 16 + col][sw]);
#pragma unroll
      for (int i = 0; i < 4; ++i)
        bfr[i] = *reinterpret_cast<const short8*>(&Bs[wc * 64 + i * 16 + col][sw]);
#pragma unroll
      for (int mi = 0; mi < 4; ++mi)
#pragma unroll
        for (int ni = 0; ni < 4; ++ni) acc[mi][ni] = mfma16(af[mi], bfr[ni], acc[mi][ni]);
    }
  }
#pragma unroll
  for (int mi = 0; mi < 4; ++mi)
#pragma unroll
    for (int ni = 0; ni < 4; ++ni)
#pragma unroll
      for (int j = 0; j < 4; ++j) {
        int m = m0 + wr * 64 + mi * 16 + grp * 4 + j;
        int n = n0 + wc * 64 + ni * 16 + col;
        float v = acc[mi][ni][j];
        if (MODE == 0) {
          int b = m >> 11, s = m & 2047;
          int h = n / 192, f = n - h * 192;
          u16 bv = f2bf(v);
          if (f < 64)
            q[(((size_t)(b * NH + h) * SEQ + s) << 6) + f] = bv;
          else if (f < 128)
            kk[(((size_t)(b * NH + h) * SEQ + s) << 6) + (f - 64)] = bv;
          else
            vt[(size_t)(b * NH + h) * (HD * SEQ) + (size_t)(s >> 5) * 2048 +
               (f - 128) * 32 + (s & 31)] = bv;
        } else {
          out[(size_t)m * N + n] = v;
        }
      }
}

// ---------------- flash attention, causal, softcap 50 ----------------
// R9 structure (known-good): 4-wave blocks, grid 1024, uniform-work pairing
// (63-i, i), split-KV x4, serial combine. Packed-f32 softmax (R11). TILED
// Vt layout (R13). T5 setprio (R15: null, kept — within noise).
// R16: (a) raw __builtin_amdgcn_exp2f (exp2f without fast-math emits a
// ~7-inst range-fixup sequence; the HW op is 1 ULP over our |arg|<=72);
// (b) diag-tile PEEL — mask code (16 cmp + 16 cndmask + kpos math) now
// compiles only into the one masked call per wave, not all 16 tiles.
// R15 accounting: 485 VALU insts/tile measured vs ~160 source-level; these
// two artifacts are the gap.
// No prefetch (R8/R12 spilled). 4 waves/SIMD is the occupancy ceiling (R10).
#define TILE_BODY(KBASE, DIAG)                                                          \
  {                                                                                     \
    int kbase = (KBASE);                                                                \
    short8 kf[4];                                                                       \
    _Pragma("unroll") for (int d0 = 0; d0 < 4; ++d0)                                    \
      kf[d0] = *reinterpret_cast<const short8*>(                                        \
          &Kb[(size_t)(kbase + ql) * HD + d0 * 16 + hi * 8]);                           \
    f32x16 sacc;                                                                        \
    _Pragma("unroll") for (int r = 0; r < 16; ++r) sacc[r] = 0.f;                       \
    __builtin_amdgcn_s_setprio(1);                                                      \
    _Pragma("unroll") for (int d0 = 0; d0 < 4; ++d0) sacc = mfma32(kf[d0], qf[d0], sacc); \
    __builtin_amdgcn_s_setprio(0);                                                      \
    const u16* Vtile = Vb + (size_t)(kbase >> 5) * 2048;                                \
    short8 vf[2][2];                                                                    \
    _Pragma("unroll") for (int c = 0; c < 2; ++c)                                       \
      _Pragma("unroll") for (int dh = 0; dh < 2; ++dh)                                  \
        vf[c][dh] = *reinterpret_cast<const short8*>(                                   \
            &Vtile[(dh * 32 + ql) * 32 + c * 16 + hi * 8]);                             \
    float p[16];                                                                        \
    _Pragma("unroll") for (int r2 = 0; r2 < 8; ++r2) {                                  \
      f32x2 s2 = {sacc[2 * r2], sacc[2 * r2 + 1]};                                      \
      f32x2 t2 = s2 * s2;                                                               \
      f32x2 u2 = __builtin_elementwise_fma(t2, C52, C32);                               \
      u2 = __builtin_elementwise_fma(t2, u2, L2E2);                                     \
      f32x2 v2 = s2 * u2;                                                               \
      float p0 = __builtin_amdgcn_exp2f(v2.x);                                          \
      float p1 = __builtin_amdgcn_exp2f(v2.y);                                          \
      if (DIAG) {                                                                       \
        int r = 2 * r2;                                                                 \
        int kpos0 = kbase + (r & 3) + 8 * (r >> 2) + 4 * hi;                            \
        int kpos1 = kbase + ((r + 1) & 3) + 8 * ((r + 1) >> 2) + 4 * hi;                \
        if (kpos0 > qbase + ql) p0 = 0.f;                                               \
        if (kpos1 > qbase + ql) p1 = 0.f;                                               \
      }                                                                                 \
      p[2 * r2] = p0;                                                                   \
      p[2 * r2 + 1] = p1;                                                               \
      lsum2 += (f32x2){p0, p1};                                                         \
    }                                                                                   \
    short8 pfrag[2];                                                                    \
    _Pragma("unroll") for (int c = 0; c < 2; ++c) {                                     \
      unsigned int a0, a1, b0, b1;                                                      \
      asm("v_cvt_pk_bf16_f32 %0, %1, %2" : "=v"(a0) : "v"(p[8 * c + 0]), "v"(p[8 * c + 1])); \
      asm("v_cvt_pk_bf16_f32 %0, %1, %2" : "=v"(a1) : "v"(p[8 * c + 2]), "v"(p[8 * c + 3])); \
      asm("v_cvt_pk_bf16_f32 %0, %1, %2" : "=v"(b0) : "v"(p[8 * c + 4]), "v"(p[8 * c + 5])); \
      asm("v_cvt_pk_bf16_f32 %0, %1, %2" : "=v"(b1) : "v"(p[8 * c + 6]), "v"(p[8 * c + 7])); \
      asm("v_permlane32_swap_b32 %0, %1" : "+v"(a0), "+v"(b0));                         \
      asm("v_permlane32_swap_b32 %0, %1" : "+v"(a1), "+v"(b1));                         \
      union { unsigned int u[4]; short8 s8; } pk;                                       \
      pk.u[0] = a0; pk.u[1] = a1; pk.u[2] = b0; pk.u[3] = b1;                           \
      pfrag[c] = pk.s8;                                                                 \
    }                                                                                   \
    __builtin_amdgcn_s_setprio(1);                                                      \
    _Pragma("unroll") for (int c = 0; c < 2; ++c) {                                     \
      xacc0 = mfma32(pfrag[c], vf[c][0], xacc0);                                        \
      xacc1 = mfma32(pfrag[c], vf[c][1], xacc1);                                        \
    }                                                                                   \
    __builtin_amdgcn_s_setprio(0);                                                      \
  }

__global__ __launch_bounds__(256, 4) void k_attn(const u16* __restrict__ Q,
                                                 const u16* __restrict__ K,
                                                 const u16* __restrict__ Vt,
                                                 u16* __restrict__ X) {
  int lin = blockIdx.x;          // 0..1023
  int xcd = lin & 7;             // dispatch round-robins XCDs
  int jj = lin >> 3;             // 0..127
  int bh = xcd * 4 + (jj & 3);   // 4 heads per XCD -> K+V 2MB/XCD, L2-resident
  int iq = jj >> 2;              // 0..31
  int tid = threadIdx.x, lane = tid & 63, w = tid >> 6;
  int ql = lane & 31, hi = lane >> 5;
  const u16* Qb = Q + (size_t)bh * SEQ * HD;
  const u16* Kb = K + (size_t)bh * SEQ * HD;
  const u16* Vb = Vt + (size_t)bh * HD * SEQ;
  int b = bh >> 4, h = bh & 15;
  size_t ob = (size_t)b * SEQ * DM + (size_t)h * HD;

  __shared__ float cbuf[64][34];  // combine: 16+16+1 f32 per lane

  const float L2E = 1.4426950408889634f;
  const f32x2 C32 = {-1.9235933878519513e-4f, -1.9235933878519513e-4f};  // -L2E/7500
  const f32x2 C52 = {3.0777494205630686e-8f, 3.0777494205630686e-8f};    // 2*L2E/(15*50^4)
  const f32x2 L2E2 = {L2E, L2E};

  for (int half = 0; half < 2; ++half) {
    int qc = half ? iq : 63 - iq;  // pair sums to 65 tiles -> uniform blocks
    int qbase = qc * 32;

    // Q fragments (B-operand): Q[qbase+ql][d0*16 + hi*8 .. +8]
    short8 qf[4];
#pragma unroll
    for (int d0 = 0; d0 < 4; ++d0)
      qf[d0] = *reinterpret_cast<const short8*>(&Qb[(size_t)(qbase + ql) * HD + d0 * 16 + hi * 8]);

    f32x16 xacc0, xacc1;
#pragma unroll
    for (int r = 0; r < 16; ++r) { xacc0[r] = 0.f; xacc1[r] = 0.f; }
    f32x2 lsum2 = {0.f, 0.f};

    // main tiles (kt < qc): mask compiled out.  diag tile (kt == qc):
    // owned by wave (qc & 3), mask active.
    for (int kt = w; kt < qc; kt += 4) TILE_BODY(kt * 32, false)
    if ((qc & 3) == w) TILE_BODY(qc * 32, true)

    float lsum = lsum2.x + lsum2.y;

    // ---- combine the 4 waves' partials (plain sums; M=0 softmax) ----
    __syncthreads();
    for (int src = 1; src < 4; ++src) {
      if (w == src) {
#pragma unroll
        for (int r = 0; r < 16; ++r) {
          if (src == 1) { cbuf[lane][r] = xacc0[r]; cbuf[lane][16 + r] = xacc1[r]; }
          else { cbuf[lane][r] += xacc0[r]; cbuf[lane][16 + r] += xacc1[r]; }
        }
        if (src == 1) cbuf[lane][32] = lsum; else cbuf[lane][32] += lsum;
      }
      __syncthreads();
    }

    if (w == 0) {
#pragma unroll
      for (int r = 0; r < 16; ++r) { xacc0[r] += cbuf[lane][r]; xacc1[r] += cbuf[lane][16 + r]; }
      lsum += cbuf[lane][32];
      // lanes q and q+32 hold the two k-half partials of row q
      lsum += __shfl_xor(lsum, 32, 64);
      float rinv = __builtin_amdgcn_rcpf(lsum);  // valid for q = ql on every lane

#pragma unroll
      for (int r = 0; r < 16; ++r) {
        int qrel = (r & 3) + 8 * (r >> 2) + 4 * hi;
        float rv = __shfl(rinv, qrel, 64);
        size_t row = ob + (size_t)(qbase + qrel) * DM;
        X[row + ql] = f2bf(xacc0[r] * rv);
        X[row + 32 + ql] = f2bf(xacc1[r] * rv);
      }
    }
    __syncthreads();  // cbuf safe for reuse by next half
  }
}

extern "C" void kernel_launch(void* const* d_in, const int* in_sizes, int n_in,
                              void* d_out, int out_size, void* d_ws, size_t ws_size,
                              hipStream_t stream) {
  const float* inputs = (const float*)d_in[0];
  const int* segpos = (const int*)d_in[1];
  // d_in[2] = mask: causal tril, known analytically — unused.
  const float* w_in = (const float*)d_in[3];
  const float* w_out = (const float*)d_in[4];
  float* out = (float*)d_out;
  char* ws = (char*)d_ws;

  size_t o = 0;
  u16* Xbf = (u16*)(ws + o); o += (size_t)4096 * 1024 * 2;   // inputs bf16; reused as attn output
  u16* WinT = (u16*)(ws + o); o += (size_t)3072 * 1024 * 2;  // w_in^T bf16
  u16* WoutT = (u16*)(ws + o); o += (size_t)1024 * 1024 * 2; // w_out^T bf16
  u16* Qb = (u16*)(ws + o); o += (size_t)NBATCH * NH * SEQ * HD * 2;
  u16* Kb = (u16*)(ws + o); o += (size_t)NBATCH * NH * SEQ * HD * 2;
  u16* Vt = (u16*)(ws + o); o += (size_t)NBATCH * NH * HD * SEQ * 2;
  float2* SC = (float2*)(ws + o); o += (size_t)SEQ * 32 * sizeof(float2);

  k_prep<<<8448, 256, 0, stream>>>(inputs, Xbf, w_in, WinT, w_out, WoutT, SC);
  k_gemm<0><<<dim3(24, 32), 256, 0, stream>>>(Xbf, WinT, 3072, Qb, Kb, Vt, nullptr);
  k_rope<<<512, 256, 0, stream>>>(Qb, Kb, segpos, SC);
  k_attn<<<1024, 256, 0, stream>>>(Qb, Kb, Vt, Xbf);
  k_gemm<1><<<dim3(8, 32), 256, 0, stream>>>(Xbf, WoutT, 1024, nullptr, nullptr, nullptr, out);
}